// Round 2
// baseline (2566.075 us; speedup 1.0000x reference)
//
#include <hip/hip_runtime.h>
#include <math.h>

// Problem constants (match reference)
constexpr int kDModel = 1024;
constexpr int kDState = 16;
constexpr int kDConv  = 4;
constexpr int kDInner = 2048;
constexpr int kDtRank = 64;
constexpr int kBatch  = 2;
constexpr int kSeq    = 2048;
constexpr int kRows   = kBatch * kSeq;   // 4096 (B*L)
constexpr int kProjW  = 2 * kDInner;     // 4096
constexpr int kXdblW  = kDtRank + 2 * kDState;  // 96

__device__ __forceinline__ float sigmoid_f(float x) {
    return 1.0f / (1.0f + __expf(-x));
}
__device__ __forceinline__ float softplus_f(float x) {
    return fmaxf(x, 0.0f) + log1pf(__expf(-fabsf(x)));
}

// ---------------------------------------------------------------------------
// Generic tiled fp32 GEMM, "NT" form: C[M,N] = A[M,K] (row-major, lda)
//                                            @ B[N,K]^T (row-major, ldb)
// EPI: 0 = none, 1 = softplus(v + bias[col])
// ---------------------------------------------------------------------------
template<int BM, int BN, int BK, int TM, int TN, int EPI>
__global__ __launch_bounds__((BM/TM)*(BN/TN))
void gemm_nt_f32(const float* __restrict__ A, int lda,
                 const float* __restrict__ B, int ldb,
                 float* __restrict__ C, int ldc,
                 int M, int N, int K,
                 const float* __restrict__ bias)
{
    constexpr int NTHR = (BM/TM)*(BN/TN);
    constexpr int TX   = BN/TN;
    constexpr int KQ   = BK/4;                 // float4 chunks along K
    constexpr int A_ITERS = (BM*KQ)/NTHR;
    constexpr int B_ITERS = (BN*KQ)/NTHR;
    static_assert((BM*KQ) % NTHR == 0 && (BN*KQ) % NTHR == 0, "loader");

    __shared__ float As[BK][BM];
    __shared__ float Bs[BK][BN];

    const int tid = threadIdx.x;
    const int tx  = tid % TX;
    const int ty  = tid / TX;
    const int bm0 = blockIdx.y * BM;
    const int bn0 = blockIdx.x * BN;

    float acc[TM][TN];
    #pragma unroll
    for (int i = 0; i < TM; ++i)
        #pragma unroll
        for (int j = 0; j < TN; ++j) acc[i][j] = 0.0f;

    for (int kt = 0; kt < K; kt += BK) {
        // ---- stage A tile (transposed into As[k][m]) ----
        #pragma unroll
        for (int it = 0; it < A_ITERS; ++it) {
            int c  = tid + it * NTHR;
            int r  = c / KQ;
            int kq = c % KQ;
            float4 v = make_float4(0.f, 0.f, 0.f, 0.f);
            int gm = bm0 + r;
            if (gm < M)
                v = *reinterpret_cast<const float4*>(A + (size_t)gm * lda + kt + kq * 4);
            As[kq*4+0][r] = v.x; As[kq*4+1][r] = v.y;
            As[kq*4+2][r] = v.z; As[kq*4+3][r] = v.w;
        }
        // ---- stage B tile ----
        #pragma unroll
        for (int it = 0; it < B_ITERS; ++it) {
            int c  = tid + it * NTHR;
            int r  = c / KQ;
            int kq = c % KQ;
            float4 v = make_float4(0.f, 0.f, 0.f, 0.f);
            int gn = bn0 + r;
            if (gn < N)
                v = *reinterpret_cast<const float4*>(B + (size_t)gn * ldb + kt + kq * 4);
            Bs[kq*4+0][r] = v.x; Bs[kq*4+1][r] = v.y;
            Bs[kq*4+2][r] = v.z; Bs[kq*4+3][r] = v.w;
        }
        __syncthreads();

        #pragma unroll
        for (int k = 0; k < BK; ++k) {
            float a[TM], b[TN];
            #pragma unroll
            for (int i = 0; i < TM/4; ++i) {
                float4 v = *reinterpret_cast<const float4*>(&As[k][ty*TM + i*4]);
                a[i*4+0] = v.x; a[i*4+1] = v.y; a[i*4+2] = v.z; a[i*4+3] = v.w;
            }
            #pragma unroll
            for (int j = 0; j < TN/4; ++j) {
                float4 v = *reinterpret_cast<const float4*>(&Bs[k][tx*TN + j*4]);
                b[j*4+0] = v.x; b[j*4+1] = v.y; b[j*4+2] = v.z; b[j*4+3] = v.w;
            }
            #pragma unroll
            for (int i = 0; i < TM; ++i)
                #pragma unroll
                for (int j = 0; j < TN; ++j)
                    acc[i][j] = fmaf(a[i], b[j], acc[i][j]);
        }
        __syncthreads();
    }

    // ---- epilogue + store ----
    const bool full = (bm0 + BM <= M) && (bn0 + BN <= N);
    if (full) {
        #pragma unroll
        for (int i = 0; i < TM; ++i) {
            float* cp = C + (size_t)(bm0 + ty*TM + i) * ldc + bn0 + tx*TN;
            #pragma unroll
            for (int j4 = 0; j4 < TN/4; ++j4) {
                int col0 = bn0 + tx*TN + j4*4;
                float e0 = acc[i][j4*4+0], e1 = acc[i][j4*4+1];
                float e2 = acc[i][j4*4+2], e3 = acc[i][j4*4+3];
                if (EPI == 1) {
                    e0 = softplus_f(e0 + bias[col0+0]);
                    e1 = softplus_f(e1 + bias[col0+1]);
                    e2 = softplus_f(e2 + bias[col0+2]);
                    e3 = softplus_f(e3 + bias[col0+3]);
                }
                *reinterpret_cast<float4*>(cp + j4*4) = make_float4(e0, e1, e2, e3);
            }
        }
    } else {
        #pragma unroll
        for (int i = 0; i < TM; ++i) {
            int gm = bm0 + ty*TM + i;
            if (gm >= M) continue;
            #pragma unroll
            for (int j = 0; j < TN; ++j) {
                int gn = bn0 + tx*TN + j;
                if (gn >= N) continue;
                float e = acc[i][j];
                if (EPI == 1) e = softplus_f(e + bias[gn]);
                C[(size_t)gm * ldc + gn] = e;
            }
        }
    }
}

// ---------------------------------------------------------------------------
// Fused depthwise causal conv1d (k=4, left-pad 3) + bias + SiLU.
// x = proj[:, 0:kDInner] (row stride kProjW). u[row, d] output, 4 d per thread.
// ---------------------------------------------------------------------------
__global__ __launch_bounds__(256)
void conv_silu_kernel(const float* __restrict__ proj,
                      const float* __restrict__ conv_w,  // [kDInner, 4]
                      const float* __restrict__ conv_b,  // [kDInner]
                      float* __restrict__ u)             // [kRows, kDInner]
{
    int idx = blockIdx.x * blockDim.x + threadIdx.x;   // one per (row, d/4)
    constexpr int D4 = kDInner / 4;
    if (idx >= kRows * D4) return;
    int d4  = idx % D4;
    int row = idx / D4;
    int t   = row % kSeq;
    int d   = d4 * 4;

    float4 w0 = *reinterpret_cast<const float4*>(conv_w + (size_t)(d+0)*4);
    float4 w1 = *reinterpret_cast<const float4*>(conv_w + (size_t)(d+1)*4);
    float4 w2 = *reinterpret_cast<const float4*>(conv_w + (size_t)(d+2)*4);
    float4 w3 = *reinterpret_cast<const float4*>(conv_w + (size_t)(d+3)*4);
    float4 bv = *reinterpret_cast<const float4*>(conv_b + d);
    float a0 = bv.x, a1 = bv.y, a2 = bv.z, a3 = bv.w;

    #pragma unroll
    for (int k = 0; k < kDConv; ++k) {
        int tt = t - (kDConv - 1) + k;
        if (tt < 0) continue;
        const float4 xv = *reinterpret_cast<const float4*>(
            proj + (size_t)(row - (kDConv - 1) + k) * kProjW + d);
        const float wk0 = (&w0.x)[k], wk1 = (&w1.x)[k];
        const float wk2 = (&w2.x)[k], wk3 = (&w3.x)[k];
        a0 = fmaf(xv.x, wk0, a0);
        a1 = fmaf(xv.y, wk1, a1);
        a2 = fmaf(xv.z, wk2, a2);
        a3 = fmaf(xv.w, wk3, a3);
    }
    a0 *= sigmoid_f(a0); a1 *= sigmoid_f(a1);
    a2 *= sigmoid_f(a2); a3 *= sigmoid_f(a3);
    *reinterpret_cast<float4*>(u + (size_t)row * kDInner + d) = make_float4(a0, a1, a2, a3);
}

// ---------------------------------------------------------------------------
// Selective scan. One thread per (b, d, s); 16 lanes (s) per channel group.
// dt lives in proj[:, 0:kDInner] (written there by the dt-GEMM); y overwrites
// it in place. Safe: the y-store's data depends (via shfl reduce) on all 16
// lanes' dt reads, so reads complete before the write; only this 16-lane
// group touches [row, d].
// ---------------------------------------------------------------------------
__global__ __launch_bounds__(256)
void scan_kernel(const float* __restrict__ u,      // [kRows, kDInner]
                 const float* __restrict__ xdbl,   // [kRows, 96]
                 const float* __restrict__ A_log,  // [kDInner, 16]
                 const float* __restrict__ D_skip, // [kDInner]
                 float* proj)  // dt read / y write @ col d; gate read @ col 2048+d
{
    int tid = blockIdx.x * blockDim.x + threadIdx.x;  // 65536 total
    int s = tid & (kDState - 1);
    int d = (tid >> 4) & (kDInner - 1);
    int b = tid >> 15;

    const float A_ds = -__expf(A_log[(size_t)d * kDState + s]);
    const float Dv   = D_skip[d];

    const float* u_p    = u    + (size_t)b * kSeq * kDInner + d;
    const float* bc_p   = xdbl + (size_t)b * kSeq * kXdblW + kDtRank + s;
    float*       proj_p = proj + (size_t)b * kSeq * kProjW;

    float h = 0.0f;
    for (int t = 0; t < kSeq; ++t) {
        const float dt_v = proj_p[d];
        const float u_v  = *u_p;
        const float Bv   = bc_p[0];
        const float Cv   = bc_p[kDState];
        const float dA   = __expf(dt_v * A_ds);
        h = fmaf(dA, h, dt_v * u_v * Bv);
        float p = h * Cv;
        // reduce over the 16 state lanes
        p += __shfl_xor(p, 1);
        p += __shfl_xor(p, 2);
        p += __shfl_xor(p, 4);
        p += __shfl_xor(p, 8);
        if (s == 0) {
            const float g  = proj_p[kDInner + d];
            const float yv = (p + u_v * Dv) * (g * sigmoid_f(g));
            proj_p[d] = yv;
        }
        u_p  += kDInner;
        bc_p += kXdblW;
        proj_p += kProjW;
    }
}

// ---------------------------------------------------------------------------
extern "C" void kernel_launch(void* const* d_in, const int* in_sizes, int n_in,
                              void* d_out, int out_size, void* d_ws, size_t ws_size,
                              hipStream_t stream)
{
    const float* hidden  = (const float*)d_in[0];
    // d_in[1] = time_deltas: clamped-but-unused in reference
    const float* w_in    = (const float*)d_in[2];
    const float* conv_w  = (const float*)d_in[3];
    const float* conv_b  = (const float*)d_in[4];
    const float* w_x     = (const float*)d_in[5];
    const float* w_dt    = (const float*)d_in[6];
    const float* b_dt    = (const float*)d_in[7];
    const float* A_log   = (const float*)d_in[8];
    const float* Dskip   = (const float*)d_in[9];
    const float* w_out   = (const float*)d_in[10];
    float* out = (float*)d_out;

    // workspace layout (floats): proj[4096*4096] | u[4096*2048] | xdbl[4096*96]
    // dt reuses proj[:, 0:2048] (x-columns dead after conv); y overwrites dt.
    // Total ~97.5 MB.
    float* proj = (float*)d_ws;
    float* u    = proj + (size_t)kRows * kProjW;
    float* xdbl = u    + (size_t)kRows * kDInner;

    // 1. in_proj: proj[4096,4096] = hidden[4096,1024] @ w_in[4096,1024]^T
    gemm_nt_f32<128,128,16,8,8,0><<<dim3(kProjW/128, kRows/128), 256, 0, stream>>>(
        hidden, kDModel, w_in, kDModel, proj, kProjW, kRows, kProjW, kDModel, nullptr);

    // 2. depthwise causal conv + SiLU -> u
    {
        int total = kRows * (kDInner / 4);
        conv_silu_kernel<<<(total + 255) / 256, 256, 0, stream>>>(proj, conv_w, conv_b, u);
    }

    // 3. x_proj: xdbl[4096,96] = u[4096,2048] @ w_x[96,2048]^T
    gemm_nt_f32<64,64,32,4,4,0><<<dim3((kXdblW + 63)/64, kRows/64), 256, 0, stream>>>(
        u, kDInner, w_x, kDInner, xdbl, kXdblW, kRows, kXdblW, kDInner, nullptr);

    // 4. dt_proj + bias + softplus -> proj[:, 0:2048] (x-cols dead after conv)
    gemm_nt_f32<128,128,16,8,8,1><<<dim3(kDInner/128, kRows/128), 256, 0, stream>>>(
        xdbl, kXdblW, w_dt, kDtRank, proj, kProjW, kRows, kDInner, kDtRank, b_dt);

    // 5. selective scan (+ skip + gate): reads dt from proj[:,0:2048], gate
    //    from proj[:,2048:4096]; writes y in place over dt.
    scan_kernel<<<(kBatch * kDInner * kDState) / 256, 256, 0, stream>>>(
        u, xdbl, A_log, Dskip, proj);

    // 6. out_proj: out[4096,1024] = y[4096,2048] @ w_out[1024,2048]^T
    gemm_nt_f32<128,128,16,8,8,0><<<dim3(kDModel/128, kRows/128), 256, 0, stream>>>(
        proj, kProjW, w_out, kDInner, out, kDModel, kRows, kDModel, kDInner, nullptr);
}

// Round 4
// 1353.497 us; speedup vs baseline: 1.8959x; 1.8959x over previous
//
#include <hip/hip_runtime.h>
#include <math.h>

// Problem constants (match reference)
constexpr int kDModel = 1024;
constexpr int kDState = 16;
constexpr int kDConv  = 4;
constexpr int kDInner = 2048;
constexpr int kDtRank = 64;
constexpr int kBatch  = 2;
constexpr int kSeq    = 2048;
constexpr int kRows   = kBatch * kSeq;   // 4096 (B*L)
constexpr int kProjW  = 2 * kDInner;     // 4096
constexpr int kXdblW  = kDtRank + 2 * kDState;  // 96
// chunked scan
constexpr int kChunks = 16;
constexpr int kLc     = kSeq / kChunks;  // 128

__device__ __forceinline__ float sigmoid_f(float x) {
    return 1.0f / (1.0f + __expf(-x));
}
__device__ __forceinline__ float softplus_f(float x) {
    return fmaxf(x, 0.0f) + log1pf(__expf(-fabsf(x)));
}

// ---------------------------------------------------------------------------
// Generic tiled fp32 GEMM, "NT" form: C[M,N] = A[M,K] (row-major, lda)
//                                            @ B[N,K]^T (row-major, ldb)
// EPI: 0 = none, 1 = softplus(v + bias[col])
// ---------------------------------------------------------------------------
template<int BM, int BN, int BK, int TM, int TN, int EPI>
__global__ __launch_bounds__((BM/TM)*(BN/TN))
void gemm_nt_f32(const float* __restrict__ A, int lda,
                 const float* __restrict__ B, int ldb,
                 float* __restrict__ C, int ldc,
                 int M, int N, int K,
                 const float* __restrict__ bias)
{
    constexpr int NTHR = (BM/TM)*(BN/TN);
    constexpr int TX   = BN/TN;
    constexpr int KQ   = BK/4;                 // float4 chunks along K
    constexpr int A_ITERS = (BM*KQ)/NTHR;
    constexpr int B_ITERS = (BN*KQ)/NTHR;
    static_assert((BM*KQ) % NTHR == 0 && (BN*KQ) % NTHR == 0, "loader");

    __shared__ float As[BK][BM];
    __shared__ float Bs[BK][BN];

    const int tid = threadIdx.x;
    const int tx  = tid % TX;
    const int ty  = tid / TX;
    const int bm0 = blockIdx.y * BM;
    const int bn0 = blockIdx.x * BN;

    float acc[TM][TN];
    #pragma unroll
    for (int i = 0; i < TM; ++i)
        #pragma unroll
        for (int j = 0; j < TN; ++j) acc[i][j] = 0.0f;

    for (int kt = 0; kt < K; kt += BK) {
        // ---- stage A tile (transposed into As[k][m]) ----
        #pragma unroll
        for (int it = 0; it < A_ITERS; ++it) {
            int c  = tid + it * NTHR;
            int r  = c / KQ;
            int kq = c % KQ;
            float4 v = make_float4(0.f, 0.f, 0.f, 0.f);
            int gm = bm0 + r;
            if (gm < M)
                v = *reinterpret_cast<const float4*>(A + (size_t)gm * lda + kt + kq * 4);
            As[kq*4+0][r] = v.x; As[kq*4+1][r] = v.y;
            As[kq*4+2][r] = v.z; As[kq*4+3][r] = v.w;
        }
        // ---- stage B tile ----
        #pragma unroll
        for (int it = 0; it < B_ITERS; ++it) {
            int c  = tid + it * NTHR;
            int r  = c / KQ;
            int kq = c % KQ;
            float4 v = make_float4(0.f, 0.f, 0.f, 0.f);
            int gn = bn0 + r;
            if (gn < N)
                v = *reinterpret_cast<const float4*>(B + (size_t)gn * ldb + kt + kq * 4);
            Bs[kq*4+0][r] = v.x; Bs[kq*4+1][r] = v.y;
            Bs[kq*4+2][r] = v.z; Bs[kq*4+3][r] = v.w;
        }
        __syncthreads();

        #pragma unroll
        for (int k = 0; k < BK; ++k) {
            float a[TM], b[TN];
            #pragma unroll
            for (int i = 0; i < TM/4; ++i) {
                float4 v = *reinterpret_cast<const float4*>(&As[k][ty*TM + i*4]);
                a[i*4+0] = v.x; a[i*4+1] = v.y; a[i*4+2] = v.z; a[i*4+3] = v.w;
            }
            #pragma unroll
            for (int j = 0; j < TN/4; ++j) {
                float4 v = *reinterpret_cast<const float4*>(&Bs[k][tx*TN + j*4]);
                b[j*4+0] = v.x; b[j*4+1] = v.y; b[j*4+2] = v.z; b[j*4+3] = v.w;
            }
            #pragma unroll
            for (int i = 0; i < TM; ++i)
                #pragma unroll
                for (int j = 0; j < TN; ++j)
                    acc[i][j] = fmaf(a[i], b[j], acc[i][j]);
        }
        __syncthreads();
    }

    // ---- epilogue + store ----
    const bool full = (bm0 + BM <= M) && (bn0 + BN <= N);
    if (full) {
        #pragma unroll
        for (int i = 0; i < TM; ++i) {
            float* cp = C + (size_t)(bm0 + ty*TM + i) * ldc + bn0 + tx*TN;
            #pragma unroll
            for (int j4 = 0; j4 < TN/4; ++j4) {
                int col0 = bn0 + tx*TN + j4*4;
                float e0 = acc[i][j4*4+0], e1 = acc[i][j4*4+1];
                float e2 = acc[i][j4*4+2], e3 = acc[i][j4*4+3];
                if (EPI == 1) {
                    e0 = softplus_f(e0 + bias[col0+0]);
                    e1 = softplus_f(e1 + bias[col0+1]);
                    e2 = softplus_f(e2 + bias[col0+2]);
                    e3 = softplus_f(e3 + bias[col0+3]);
                }
                *reinterpret_cast<float4*>(cp + j4*4) = make_float4(e0, e1, e2, e3);
            }
        }
    } else {
        #pragma unroll
        for (int i = 0; i < TM; ++i) {
            int gm = bm0 + ty*TM + i;
            if (gm >= M) continue;
            #pragma unroll
            for (int j = 0; j < TN; ++j) {
                int gn = bn0 + tx*TN + j;
                if (gn >= N) continue;
                float e = acc[i][j];
                if (EPI == 1) e = softplus_f(e + bias[gn]);
                C[(size_t)gm * ldc + gn] = e;
            }
        }
    }
}

// ---------------------------------------------------------------------------
// Fused depthwise causal conv1d (k=4, left-pad 3) + bias + SiLU.
// x = proj[:, 0:kDInner] (row stride kProjW). u[row, d] output, 4 d per thread.
// ---------------------------------------------------------------------------
__global__ __launch_bounds__(256)
void conv_silu_kernel(const float* __restrict__ proj,
                      const float* __restrict__ conv_w,  // [kDInner, 4]
                      const float* __restrict__ conv_b,  // [kDInner]
                      float* __restrict__ u)             // [kRows, kDInner]
{
    int idx = blockIdx.x * blockDim.x + threadIdx.x;   // one per (row, d/4)
    constexpr int D4 = kDInner / 4;
    if (idx >= kRows * D4) return;
    int d4  = idx % D4;
    int row = idx / D4;
    int t   = row % kSeq;
    int d   = d4 * 4;

    float4 w0 = *reinterpret_cast<const float4*>(conv_w + (size_t)(d+0)*4);
    float4 w1 = *reinterpret_cast<const float4*>(conv_w + (size_t)(d+1)*4);
    float4 w2 = *reinterpret_cast<const float4*>(conv_w + (size_t)(d+2)*4);
    float4 w3 = *reinterpret_cast<const float4*>(conv_w + (size_t)(d+3)*4);
    float4 bv = *reinterpret_cast<const float4*>(conv_b + d);
    float a0 = bv.x, a1 = bv.y, a2 = bv.z, a3 = bv.w;

    #pragma unroll
    for (int k = 0; k < kDConv; ++k) {
        int tt = t - (kDConv - 1) + k;
        if (tt < 0) continue;
        const float4 xv = *reinterpret_cast<const float4*>(
            proj + (size_t)(row - (kDConv - 1) + k) * kProjW + d);
        const float wk0 = (&w0.x)[k], wk1 = (&w1.x)[k];
        const float wk2 = (&w2.x)[k], wk3 = (&w3.x)[k];
        a0 = fmaf(xv.x, wk0, a0);
        a1 = fmaf(xv.y, wk1, a1);
        a2 = fmaf(xv.z, wk2, a2);
        a3 = fmaf(xv.w, wk3, a3);
    }
    a0 *= sigmoid_f(a0); a1 *= sigmoid_f(a1);
    a2 *= sigmoid_f(a2); a3 *= sigmoid_f(a3);
    *reinterpret_cast<float4*>(u + (size_t)row * kDInner + d) = make_float4(a0, a1, a2, a3);
}

// ---------------------------------------------------------------------------
// Chunked parallel scan, pass 1: per-chunk local scan (h from 0) + running
// product P of the dA factors. Thread per (b, d, s, c); full occupancy.
// dA values here are bit-identical to pass 3's recompute (same __expf inputs).
// ---------------------------------------------------------------------------
__global__ __launch_bounds__(256)
void scan_pass1(const float* __restrict__ proj,   // dt @ [row*kProjW + d]
                const float* __restrict__ u,      // [kRows, kDInner]
                const float* __restrict__ xdbl,   // [kRows, 96]
                const float* __restrict__ A_log,  // [kDInner, 16]
                float* __restrict__ htail,        // [B, D, C, S]
                float* __restrict__ Pprod)        // [B, D, C, S]
{
    int tid = blockIdx.x * blockDim.x + threadIdx.x;  // B*D*S*C = 1,048,576
    int s = tid & (kDState - 1);
    int d = (tid >> 4) & (kDInner - 1);
    int g = tid >> 15;             // 0..31
    int c = g & (kChunks - 1);
    int b = g >> 4;

    const float A_ds = -__expf(A_log[(size_t)d * kDState + s]);
    const int t0 = c * kLc;

    const float* dt_p = proj + (size_t)(b * kSeq + t0) * kProjW + d;
    const float* u_p  = u    + (size_t)(b * kSeq + t0) * kDInner + d;
    const float* b_p  = xdbl + (size_t)(b * kSeq + t0) * kXdblW + kDtRank + s;

    float h = 0.0f, P = 1.0f;
    for (int t = 0; t < kLc; ++t) {
        const float dt_v = *dt_p;
        const float u_v  = *u_p;
        const float Bv   = *b_p;
        const float dA   = __expf(dt_v * A_ds);
        h = fmaf(dA, h, dt_v * u_v * Bv);
        P *= dA;
        dt_p += kProjW; u_p += kDInner; b_p += kXdblW;
    }
    size_t idx = (((size_t)(b * kDInner + d)) * kChunks + c) * kDState + s;
    htail[idx] = h;
    Pprod[idx] = P;
}

// ---------------------------------------------------------------------------
// Pass 2: sequential combine over the 16 chunk summaries.
// In-place: hbuf holds h_local on entry, h_init (state entering chunk) on exit.
// ---------------------------------------------------------------------------
__global__ __launch_bounds__(256)
void scan_pass2(float* hbuf,                       // [B, D, C, S] in/out
                const float* __restrict__ Pprod)   // [B, D, C, S]
{
    int tid = blockIdx.x * blockDim.x + threadIdx.x;  // B*D*S = 65536
    int s = tid & (kDState - 1);
    int d = (tid >> 4) & (kDInner - 1);
    int b = tid >> 15;

    size_t base = ((size_t)(b * kDInner + d)) * kChunks * kDState + s;
    float hs = 0.0f;
    for (int c = 0; c < kChunks; ++c) {
        size_t ix = base + (size_t)c * kDState;
        const float ht = hbuf[ix];
        const float P  = Pprod[ix];
        hbuf[ix] = hs;               // h_init for chunk c
        hs = fmaf(P, hs, ht);
    }
}

// ---------------------------------------------------------------------------
// Pass 3: re-run scan per chunk from h_init; same per-step fp32 ops as the
// reference. Fused skip + gate; y overwrites dt in proj[:, 0:kDInner].
// ---------------------------------------------------------------------------
__global__ __launch_bounds__(256)
void scan_pass3(const float* __restrict__ u,      // [kRows, kDInner]
                const float* __restrict__ xdbl,   // [kRows, 96]
                const float* __restrict__ A_log,  // [kDInner, 16]
                const float* __restrict__ D_skip, // [kDInner]
                const float* __restrict__ hinit,  // [B, D, C, S]
                float* proj)  // dt read / y write @ col d; gate read @ col 2048+d
{
    int tid = blockIdx.x * blockDim.x + threadIdx.x;  // B*D*S*C = 1,048,576
    int s = tid & (kDState - 1);
    int d = (tid >> 4) & (kDInner - 1);
    int g = tid >> 15;
    int c = g & (kChunks - 1);
    int b = g >> 4;

    const float A_ds = -__expf(A_log[(size_t)d * kDState + s]);
    const float Dv   = D_skip[d];
    const int t0 = c * kLc;

    const float* u_p    = u    + (size_t)(b * kSeq + t0) * kDInner + d;
    const float* bc_p   = xdbl + (size_t)(b * kSeq + t0) * kXdblW + kDtRank + s;
    float*       proj_p = proj + (size_t)(b * kSeq + t0) * kProjW;

    float h = hinit[(((size_t)(b * kDInner + d)) * kChunks + c) * kDState + s];

    for (int t = 0; t < kLc; ++t) {
        const float dt_v = proj_p[d];
        const float u_v  = *u_p;
        const float Bv   = bc_p[0];
        const float Cv   = bc_p[kDState];
        const float dA   = __expf(dt_v * A_ds);
        h = fmaf(dA, h, dt_v * u_v * Bv);
        float p = h * Cv;
        p += __shfl_xor(p, 1);
        p += __shfl_xor(p, 2);
        p += __shfl_xor(p, 4);
        p += __shfl_xor(p, 8);
        if (s == 0) {
            const float gt = proj_p[kDInner + d];
            proj_p[d] = (p + u_v * Dv) * (gt * sigmoid_f(gt));
        }
        u_p  += kDInner;
        bc_p += kXdblW;
        proj_p += kProjW;
    }
}

// ---------------------------------------------------------------------------
extern "C" void kernel_launch(void* const* d_in, const int* in_sizes, int n_in,
                              void* d_out, int out_size, void* d_ws, size_t ws_size,
                              hipStream_t stream)
{
    const float* hidden  = (const float*)d_in[0];
    // d_in[1] = time_deltas: clamped-but-unused in reference
    const float* w_in    = (const float*)d_in[2];
    const float* conv_w  = (const float*)d_in[3];
    const float* conv_b  = (const float*)d_in[4];
    const float* w_x     = (const float*)d_in[5];
    const float* w_dt    = (const float*)d_in[6];
    const float* b_dt    = (const float*)d_in[7];
    const float* A_log   = (const float*)d_in[8];
    const float* Dskip   = (const float*)d_in[9];
    const float* w_out   = (const float*)d_in[10];
    float* out = (float*)d_out;

    // ws layout (floats): proj[4096*4096] | u[4096*2048] | xdbl[4096*96]
    //                     | htail[B*D*C*S] | Pprod[B*D*C*S]          (~106 MB)
    // dt reuses proj[:, 0:2048] (x-cols dead after conv); y overwrites dt.
    float* proj  = (float*)d_ws;
    float* u     = proj  + (size_t)kRows * kProjW;
    float* xdbl  = u     + (size_t)kRows * kDInner;
    float* htail = xdbl  + (size_t)kRows * kXdblW;
    float* Pprod = htail + (size_t)kBatch * kDInner * kChunks * kDState;

    // 1. in_proj: proj[4096,4096] = hidden[4096,1024] @ w_in[4096,1024]^T
    gemm_nt_f32<128,128,16,8,8,0><<<dim3(kProjW/128, kRows/128), 256, 0, stream>>>(
        hidden, kDModel, w_in, kDModel, proj, kProjW, kRows, kProjW, kDModel, nullptr);

    // 2. depthwise causal conv + SiLU -> u
    {
        int total = kRows * (kDInner / 4);
        conv_silu_kernel<<<(total + 255) / 256, 256, 0, stream>>>(proj, conv_w, conv_b, u);
    }

    // 3. x_proj: xdbl[4096,96] = u[4096,2048] @ w_x[96,2048]^T
    gemm_nt_f32<64,64,32,4,4,0><<<dim3((kXdblW + 63)/64, kRows/64), 256, 0, stream>>>(
        u, kDInner, w_x, kDInner, xdbl, kXdblW, kRows, kXdblW, kDInner, nullptr);

    // 4. dt_proj + bias + softplus -> proj[:, 0:2048] (x-cols dead after conv)
    gemm_nt_f32<128,128,16,8,8,1><<<dim3(kDInner/128, kRows/128), 256, 0, stream>>>(
        xdbl, kXdblW, w_dt, kDtRank, proj, kProjW, kRows, kDInner, kDtRank, b_dt);

    // 5. chunked selective scan (+ skip + gate), y -> proj[:, 0:2048]
    {
        int n1 = kBatch * kDInner * kDState * kChunks;   // 1,048,576
        scan_pass1<<<n1 / 256, 256, 0, stream>>>(proj, u, xdbl, A_log, htail, Pprod);
        int n2 = kBatch * kDInner * kDState;             // 65,536
        scan_pass2<<<n2 / 256, 256, 0, stream>>>(htail, Pprod);
        scan_pass3<<<n1 / 256, 256, 0, stream>>>(u, xdbl, A_log, Dskip, htail, proj);
    }

    // 6. out_proj: out[4096,1024] = y[4096,2048] @ w_out[1024,2048]^T
    gemm_nt_f32<128,128,16,8,8,0><<<dim3(kDModel/128, kRows/128), 256, 0, stream>>>(
        proj, kProjW, w_out, kDInner, out, kDModel, kRows, kDModel, kDInner, nullptr);
}

// Round 6
// 826.132 us; speedup vs baseline: 3.1061x; 1.6384x over previous
//
#include <hip/hip_runtime.h>
#include <math.h>

// Problem constants (match reference)
constexpr int kDModel = 1024;
constexpr int kDState = 16;
constexpr int kDConv  = 4;
constexpr int kDInner = 2048;
constexpr int kDtRank = 64;
constexpr int kBatch  = 2;
constexpr int kSeq    = 2048;
constexpr int kRows   = kBatch * kSeq;   // 4096 (B*L)
constexpr int kProjW  = 2 * kDInner;     // 4096
constexpr int kXdblW  = kDtRank + 2 * kDState;  // 96
// chunked scan
constexpr int kChunks = 16;
constexpr int kLc     = kSeq / kChunks;  // 128

__device__ __forceinline__ float sigmoid_f(float x) {
    return 1.0f / (1.0f + __expf(-x));
}
__device__ __forceinline__ float softplus_f(float x) {
    return fmaxf(x, 0.0f) + log1pf(__expf(-fabsf(x)));
}
// fp32 -> bf16 (RNE) and back, as raw ushort bit patterns
__device__ __forceinline__ unsigned short f2bf(float x) {
    unsigned int u = __float_as_uint(x);
    u += 0x7FFFu + ((u >> 16) & 1u);
    return (unsigned short)(u >> 16);
}
__device__ __forceinline__ float bf2f(unsigned short h) {
    return __uint_as_float(((unsigned int)h) << 16);
}

// ---------------------------------------------------------------------------
// Generic tiled fp32 GEMM, "NT" form (kept for x_proj / dt_proj / fallback)
// EPI: 0 = none, 1 = softplus(v + bias[col])
// ---------------------------------------------------------------------------
template<int BM, int BN, int BK, int TM, int TN, int EPI>
__global__ __launch_bounds__((BM/TM)*(BN/TN))
void gemm_nt_f32(const float* __restrict__ A, int lda,
                 const float* __restrict__ B, int ldb,
                 float* __restrict__ C, int ldc,
                 int M, int N, int K,
                 const float* __restrict__ bias)
{
    constexpr int NTHR = (BM/TM)*(BN/TN);
    constexpr int TX   = BN/TN;
    constexpr int KQ   = BK/4;
    constexpr int A_ITERS = (BM*KQ)/NTHR;
    constexpr int B_ITERS = (BN*KQ)/NTHR;
    static_assert((BM*KQ) % NTHR == 0 && (BN*KQ) % NTHR == 0, "loader");

    __shared__ float As[BK][BM];
    __shared__ float Bs[BK][BN];

    const int tid = threadIdx.x;
    const int tx  = tid % TX;
    const int ty  = tid / TX;
    const int bm0 = blockIdx.y * BM;
    const int bn0 = blockIdx.x * BN;

    float acc[TM][TN];
    #pragma unroll
    for (int i = 0; i < TM; ++i)
        #pragma unroll
        for (int j = 0; j < TN; ++j) acc[i][j] = 0.0f;

    for (int kt = 0; kt < K; kt += BK) {
        #pragma unroll
        for (int it = 0; it < A_ITERS; ++it) {
            int c  = tid + it * NTHR;
            int r  = c / KQ;
            int kq = c % KQ;
            float4 v = make_float4(0.f, 0.f, 0.f, 0.f);
            int gm = bm0 + r;
            if (gm < M)
                v = *reinterpret_cast<const float4*>(A + (size_t)gm * lda + kt + kq * 4);
            As[kq*4+0][r] = v.x; As[kq*4+1][r] = v.y;
            As[kq*4+2][r] = v.z; As[kq*4+3][r] = v.w;
        }
        #pragma unroll
        for (int it = 0; it < B_ITERS; ++it) {
            int c  = tid + it * NTHR;
            int r  = c / KQ;
            int kq = c % KQ;
            float4 v = make_float4(0.f, 0.f, 0.f, 0.f);
            int gn = bn0 + r;
            if (gn < N)
                v = *reinterpret_cast<const float4*>(B + (size_t)gn * ldb + kt + kq * 4);
            Bs[kq*4+0][r] = v.x; Bs[kq*4+1][r] = v.y;
            Bs[kq*4+2][r] = v.z; Bs[kq*4+3][r] = v.w;
        }
        __syncthreads();

        #pragma unroll
        for (int k = 0; k < BK; ++k) {
            float a[TM], b[TN];
            #pragma unroll
            for (int i = 0; i < TM/4; ++i) {
                float4 v = *reinterpret_cast<const float4*>(&As[k][ty*TM + i*4]);
                a[i*4+0] = v.x; a[i*4+1] = v.y; a[i*4+2] = v.z; a[i*4+3] = v.w;
            }
            #pragma unroll
            for (int j = 0; j < TN/4; ++j) {
                float4 v = *reinterpret_cast<const float4*>(&Bs[k][tx*TN + j*4]);
                b[j*4+0] = v.x; b[j*4+1] = v.y; b[j*4+2] = v.z; b[j*4+3] = v.w;
            }
            #pragma unroll
            for (int i = 0; i < TM; ++i)
                #pragma unroll
                for (int j = 0; j < TN; ++j)
                    acc[i][j] = fmaf(a[i], b[j], acc[i][j]);
        }
        __syncthreads();
    }

    const bool full = (bm0 + BM <= M) && (bn0 + BN <= N);
    if (full) {
        #pragma unroll
        for (int i = 0; i < TM; ++i) {
            float* cp = C + (size_t)(bm0 + ty*TM + i) * ldc + bn0 + tx*TN;
            #pragma unroll
            for (int j4 = 0; j4 < TN/4; ++j4) {
                int col0 = bn0 + tx*TN + j4*4;
                float e0 = acc[i][j4*4+0], e1 = acc[i][j4*4+1];
                float e2 = acc[i][j4*4+2], e3 = acc[i][j4*4+3];
                if (EPI == 1) {
                    e0 = softplus_f(e0 + bias[col0+0]);
                    e1 = softplus_f(e1 + bias[col0+1]);
                    e2 = softplus_f(e2 + bias[col0+2]);
                    e3 = softplus_f(e3 + bias[col0+3]);
                }
                *reinterpret_cast<float4*>(cp + j4*4) = make_float4(e0, e1, e2, e3);
            }
        }
    } else {
        #pragma unroll
        for (int i = 0; i < TM; ++i) {
            int gm = bm0 + ty*TM + i;
            if (gm >= M) continue;
            #pragma unroll
            for (int j = 0; j < TN; ++j) {
                int gn = bn0 + tx*TN + j;
                if (gn >= N) continue;
                float e = acc[i][j];
                if (EPI == 1) e = softplus_f(e + bias[gn]);
                C[(size_t)gm * ldc + gn] = e;
            }
        }
    }
}

// ---------------------------------------------------------------------------
// bf16x3 split: x -> (hi, lo) bf16 pairs. n must be divisible by 4.
// ---------------------------------------------------------------------------
__global__ __launch_bounds__(256)
void split_bf16_kernel(const float* __restrict__ x,
                       unsigned short* __restrict__ h,
                       unsigned short* __restrict__ l, int n)
{
    int i = (blockIdx.x * blockDim.x + threadIdx.x) * 4;
    if (i >= n) return;
    float4 v = *reinterpret_cast<const float4*>(x + i);
    ushort4 hv, lv;
    hv.x = f2bf(v.x); lv.x = f2bf(v.x - bf2f(hv.x));
    hv.y = f2bf(v.y); lv.y = f2bf(v.y - bf2f(hv.y));
    hv.z = f2bf(v.z); lv.z = f2bf(v.z - bf2f(hv.z));
    hv.w = f2bf(v.w); lv.w = f2bf(v.w - bf2f(hv.w));
    *reinterpret_cast<ushort4*>(h + i) = hv;
    *reinterpret_cast<ushort4*>(l + i) = lv;
}

// ---------------------------------------------------------------------------
// bf16x3 MFMA GEMM: C[M,N] fp32 = A[M,K] @ B[N,K]^T, A/B given as bf16 hi/lo.
// 128x128 tile, 4 waves (2x2), 16x16x32 MFMA, 3 MFMA per fragment pair
// (hi*hi + hi*lo + lo*hi). Linear LDS + global_load_lds width=16 (m97-style).
// All dims must divide the tile (true for our shapes).
// ---------------------------------------------------------------------------
typedef __attribute__((ext_vector_type(8))) short bf16x8;   // 8 bf16 = 4 VGPR
typedef __attribute__((ext_vector_type(4))) float f32x4;    // C/D frag

__device__ __forceinline__ void gl_lds16(const unsigned short* g, unsigned short* l) {
    __builtin_amdgcn_global_load_lds(
        (const __attribute__((address_space(1))) unsigned int*)g,
        (__attribute__((address_space(3))) unsigned int*)l, 16, 0, 0);
}

__global__ __launch_bounds__(256, 2)
void gemm_bf16x3(const unsigned short* __restrict__ Ah,
                 const unsigned short* __restrict__ Al,
                 const unsigned short* __restrict__ Bh,
                 const unsigned short* __restrict__ Bl,
                 float* __restrict__ C, int ldc, int K)
{
    __shared__ __align__(16) unsigned short sA[2][128*32];  // [hi/lo][row][k]
    __shared__ __align__(16) unsigned short sB[2][128*32];

    const int tid  = threadIdx.x;
    const int w    = tid >> 6;          // wave 0..3
    const int lane = tid & 63;
    const int wr   = w >> 1, wc = w & 1;
    const int brow = blockIdx.y * 128;
    const int bcol = blockIdx.x * 128;

    // staging: wave w covers tile rows [w*32, w*32+32); two 16-row instrs.
    const int srow = w * 32 + (lane >> 2);     // tile row for this lane
    const int kch  = (lane & 3) * 8;           // bf16 offset within 32-wide k
    const unsigned short* gAh = Ah + (size_t)(brow + srow) * K + kch;
    const unsigned short* gAl = Al + (size_t)(brow + srow) * K + kch;
    const unsigned short* gBh = Bh + (size_t)(bcol + srow) * K + kch;
    const unsigned short* gBl = Bl + (size_t)(bcol + srow) * K + kch;
    unsigned short* lAh = &sA[0][(w*32)*32];
    unsigned short* lAl = &sA[1][(w*32)*32];
    unsigned short* lBh = &sB[0][(w*32)*32];
    unsigned short* lBl = &sB[1][(w*32)*32];

    f32x4 acc[4][4];
    #pragma unroll
    for (int i = 0; i < 4; ++i)
        #pragma unroll
        for (int j = 0; j < 4; ++j) acc[i][j] = (f32x4){0.f, 0.f, 0.f, 0.f};

    const int fr = lane & 15;            // fragment row (m or n within 16)
    const int k8 = (lane >> 4) * 8;      // fragment k offset

    for (int kt = 0; kt < K; kt += 32) {
        gl_lds16(gAh,            lAh);
        gl_lds16(gAh + 16 * K,   lAh + 512);
        gl_lds16(gAl,            lAl);
        gl_lds16(gAl + 16 * K,   lAl + 512);
        gl_lds16(gBh,            lBh);
        gl_lds16(gBh + 16 * K,   lBh + 512);
        gl_lds16(gBl,            lBl);
        gl_lds16(gBl + 16 * K,   lBl + 512);
        gAh += 32; gAl += 32; gBh += 32; gBl += 32;
        asm volatile("s_waitcnt vmcnt(0)" ::: "memory");
        __syncthreads();

        bf16x8 ah[4], al[4], bh[4], bl[4];
        #pragma unroll
        for (int i = 0; i < 4; ++i) {
            int ar = (wr*64 + i*16 + fr) * 32 + k8;
            int br = (wc*64 + i*16 + fr) * 32 + k8;
            ah[i] = *reinterpret_cast<const bf16x8*>(&sA[0][ar]);
            al[i] = *reinterpret_cast<const bf16x8*>(&sA[1][ar]);
            bh[i] = *reinterpret_cast<const bf16x8*>(&sB[0][br]);
            bl[i] = *reinterpret_cast<const bf16x8*>(&sB[1][br]);
        }
        #pragma unroll
        for (int i = 0; i < 4; ++i)
            #pragma unroll
            for (int j = 0; j < 4; ++j) {
                acc[i][j] = __builtin_amdgcn_mfma_f32_16x16x32_bf16(ah[i], bh[j], acc[i][j], 0, 0, 0);
                acc[i][j] = __builtin_amdgcn_mfma_f32_16x16x32_bf16(ah[i], bl[j], acc[i][j], 0, 0, 0);
                acc[i][j] = __builtin_amdgcn_mfma_f32_16x16x32_bf16(al[i], bh[j], acc[i][j], 0, 0, 0);
            }
        __syncthreads();
    }

    // epilogue: C/D layout col = lane&15, row = (lane>>4)*4 + reg  [m89/m91]
    const int crow0 = brow + wr*64 + (lane >> 4) * 4;
    const int ccol0 = bcol + wc*64 + (lane & 15);
    #pragma unroll
    for (int i = 0; i < 4; ++i)
        #pragma unroll
        for (int j = 0; j < 4; ++j) {
            float* cp = C + (size_t)(crow0 + i*16) * ldc + ccol0 + j*16;
            #pragma unroll
            for (int r = 0; r < 4; ++r)
                cp[(size_t)r * ldc] = acc[i][j][r];
        }
}

// ---------------------------------------------------------------------------
// Fused depthwise causal conv1d (k=4) + bias + SiLU (unchanged)
// ---------------------------------------------------------------------------
__global__ __launch_bounds__(256)
void conv_silu_kernel(const float* __restrict__ proj,
                      const float* __restrict__ conv_w,
                      const float* __restrict__ conv_b,
                      float* __restrict__ u)
{
    int idx = blockIdx.x * blockDim.x + threadIdx.x;
    constexpr int D4 = kDInner / 4;
    if (idx >= kRows * D4) return;
    int d4  = idx % D4;
    int row = idx / D4;
    int t   = row % kSeq;
    int d   = d4 * 4;

    float4 w0 = *reinterpret_cast<const float4*>(conv_w + (size_t)(d+0)*4);
    float4 w1 = *reinterpret_cast<const float4*>(conv_w + (size_t)(d+1)*4);
    float4 w2 = *reinterpret_cast<const float4*>(conv_w + (size_t)(d+2)*4);
    float4 w3 = *reinterpret_cast<const float4*>(conv_w + (size_t)(d+3)*4);
    float4 bv = *reinterpret_cast<const float4*>(conv_b + d);
    float a0 = bv.x, a1 = bv.y, a2 = bv.z, a3 = bv.w;

    #pragma unroll
    for (int k = 0; k < kDConv; ++k) {
        int tt = t - (kDConv - 1) + k;
        if (tt < 0) continue;
        const float4 xv = *reinterpret_cast<const float4*>(
            proj + (size_t)(row - (kDConv - 1) + k) * kProjW + d);
        const float wk0 = (&w0.x)[k], wk1 = (&w1.x)[k];
        const float wk2 = (&w2.x)[k], wk3 = (&w3.x)[k];
        a0 = fmaf(xv.x, wk0, a0);
        a1 = fmaf(xv.y, wk1, a1);
        a2 = fmaf(xv.z, wk2, a2);
        a3 = fmaf(xv.w, wk3, a3);
    }
    a0 *= sigmoid_f(a0); a1 *= sigmoid_f(a1);
    a2 *= sigmoid_f(a2); a3 *= sigmoid_f(a3);
    *reinterpret_cast<float4*>(u + (size_t)row * kDInner + d) = make_float4(a0, a1, a2, a3);
}

// ---------------------------------------------------------------------------
// Chunked scan passes (pass1/pass2 unchanged)
// ---------------------------------------------------------------------------
__global__ __launch_bounds__(256)
void scan_pass1(const float* __restrict__ proj,
                const float* __restrict__ u,
                const float* __restrict__ xdbl,
                const float* __restrict__ A_log,
                float* __restrict__ htail,
                float* __restrict__ Pprod)
{
    int tid = blockIdx.x * blockDim.x + threadIdx.x;
    int s = tid & (kDState - 1);
    int d = (tid >> 4) & (kDInner - 1);
    int g = tid >> 15;
    int c = g & (kChunks - 1);
    int b = g >> 4;

    const float A_ds = -__expf(A_log[(size_t)d * kDState + s]);
    const int t0 = c * kLc;

    const float* dt_p = proj + (size_t)(b * kSeq + t0) * kProjW + d;
    const float* u_p  = u    + (size_t)(b * kSeq + t0) * kDInner + d;
    const float* b_p  = xdbl + (size_t)(b * kSeq + t0) * kXdblW + kDtRank + s;

    float h = 0.0f, P = 1.0f;
    for (int t = 0; t < kLc; ++t) {
        const float dt_v = *dt_p;
        const float u_v  = *u_p;
        const float Bv   = *b_p;
        const float dA   = __expf(dt_v * A_ds);
        h = fmaf(dA, h, dt_v * u_v * Bv);
        P *= dA;
        dt_p += kProjW; u_p += kDInner; b_p += kXdblW;
    }
    size_t idx = (((size_t)(b * kDInner + d)) * kChunks + c) * kDState + s;
    htail[idx] = h;
    Pprod[idx] = P;
}

__global__ __launch_bounds__(256)
void scan_pass2(float* hbuf, const float* __restrict__ Pprod)
{
    int tid = blockIdx.x * blockDim.x + threadIdx.x;
    int s = tid & (kDState - 1);
    int d = (tid >> 4) & (kDInner - 1);
    int b = tid >> 15;

    size_t base = ((size_t)(b * kDInner + d)) * kChunks * kDState + s;
    float hs = 0.0f;
    for (int c = 0; c < kChunks; ++c) {
        size_t ix = base + (size_t)c * kDState;
        const float ht = hbuf[ix];
        const float P  = Pprod[ix];
        hbuf[ix] = hs;
        hs = fmaf(P, hs, ht);
    }
}

// Pass 3: y = (scan + skip) * silu(gate). bf16_mode: write y as bf16 hi/lo
// (feeds MFMA out_proj); else write fp32 into proj (fallback).
__global__ __launch_bounds__(256)
void scan_pass3(const float* __restrict__ u,
                const float* __restrict__ xdbl,
                const float* __restrict__ A_log,
                const float* __restrict__ D_skip,
                const float* __restrict__ hinit,
                float* proj,
                unsigned short* __restrict__ yh,
                unsigned short* __restrict__ yl,
                int bf16_mode)
{
    int tid = blockIdx.x * blockDim.x + threadIdx.x;
    int s = tid & (kDState - 1);
    int d = (tid >> 4) & (kDInner - 1);
    int g = tid >> 15;
    int c = g & (kChunks - 1);
    int b = g >> 4;

    const float A_ds = -__expf(A_log[(size_t)d * kDState + s]);
    const float Dv   = D_skip[d];
    const int t0 = c * kLc;

    const float* u_p    = u    + (size_t)(b * kSeq + t0) * kDInner + d;
    const float* bc_p   = xdbl + (size_t)(b * kSeq + t0) * kXdblW + kDtRank + s;
    float*       proj_p = proj + (size_t)(b * kSeq + t0) * kProjW;
    size_t       yoff   = (size_t)(b * kSeq + t0) * kDInner + d;

    float h = hinit[(((size_t)(b * kDInner + d)) * kChunks + c) * kDState + s];

    for (int t = 0; t < kLc; ++t) {
        const float dt_v = proj_p[d];
        const float u_v  = *u_p;
        const float Bv   = bc_p[0];
        const float Cv   = bc_p[kDState];
        const float dA   = __expf(dt_v * A_ds);
        h = fmaf(dA, h, dt_v * u_v * Bv);
        float p = h * Cv;
        p += __shfl_xor(p, 1);
        p += __shfl_xor(p, 2);
        p += __shfl_xor(p, 4);
        p += __shfl_xor(p, 8);
        if (s == 0) {
            const float gt = proj_p[kDInner + d];
            const float yv = (p + u_v * Dv) * (gt * sigmoid_f(gt));
            if (bf16_mode) {
                unsigned short hv = f2bf(yv);
                yh[yoff] = hv;
                yl[yoff] = f2bf(yv - bf2f(hv));
            } else {
                proj_p[d] = yv;
            }
        }
        u_p  += kDInner;
        bc_p += kXdblW;
        proj_p += kProjW;
        yoff += kDInner;
    }
}

// ---------------------------------------------------------------------------
extern "C" void kernel_launch(void* const* d_in, const int* in_sizes, int n_in,
                              void* d_out, int out_size, void* d_ws, size_t ws_size,
                              hipStream_t stream)
{
    const float* hidden  = (const float*)d_in[0];
    const float* w_in    = (const float*)d_in[2];
    const float* conv_w  = (const float*)d_in[3];
    const float* conv_b  = (const float*)d_in[4];
    const float* w_x     = (const float*)d_in[5];
    const float* w_dt    = (const float*)d_in[6];
    const float* b_dt    = (const float*)d_in[7];
    const float* A_log   = (const float*)d_in[8];
    const float* Dskip   = (const float*)d_in[9];
    const float* w_out   = (const float*)d_in[10];
    float* out = (float*)d_out;

    // base ws layout (floats): proj | u | xdbl | htail | Pprod  (~110.6 MB)
    float* proj  = (float*)d_ws;
    float* u     = proj  + (size_t)kRows * kProjW;
    float* xdbl  = u     + (size_t)kRows * kDInner;
    float* htail = xdbl  + (size_t)kRows * kXdblW;
    float* Pprod = htail + (size_t)kBatch * kDInner * kChunks * kDState;
    float* base_end = Pprod + (size_t)kBatch * kDInner * kChunks * kDState;

    // bf16x3 extension: splitbuf 32MB (Ah|Al|Wh|Wl, later aliased yh|yl) + 8MB (Woh|Wol)
    unsigned short* sp = (unsigned short*)base_end;
    const size_t nHid = (size_t)kRows * kDModel;      // 4,194,304
    const size_t nWin = (size_t)kProjW * kDModel;     // 4,194,304
    const size_t nWout = (size_t)kDModel * kDInner;   // 2,097,152
    const size_t nY   = (size_t)kRows * kDInner;      // 8,388,608
    unsigned short* Ah  = sp;
    unsigned short* Al  = Ah + nHid;
    unsigned short* Wh  = Al + nHid;
    unsigned short* Wl  = Wh + nWin;
    unsigned short* yh  = sp;                // alias over Ah/Al (dead by pass3)
    unsigned short* yl  = sp + nY;           // alias over Wh/Wl
    unsigned short* Woh = sp + 2 * nY;
    unsigned short* Wol = Woh + nWout;
    const size_t need_bf16 = (size_t)((char*)(Wol + nWout) - (char*)d_ws);
    const bool use_bf16 = ws_size >= need_bf16;

    if (use_bf16) {
        // 0. precision splits
        split_bf16_kernel<<<(int)(nHid / 4 / 256), 256, 0, stream>>>(hidden, Ah, Al, (int)nHid);
        split_bf16_kernel<<<(int)(nWin / 4 / 256), 256, 0, stream>>>(w_in, Wh, Wl, (int)nWin);
        split_bf16_kernel<<<(int)(nWout / 4 / 256), 256, 0, stream>>>(w_out, Woh, Wol, (int)nWout);
        // 1. in_proj via bf16x3 MFMA
        gemm_bf16x3<<<dim3(kProjW/128, kRows/128), 256, 0, stream>>>(
            Ah, Al, Wh, Wl, proj, kProjW, kDModel);
    } else {
        gemm_nt_f32<128,128,16,8,8,0><<<dim3(kProjW/128, kRows/128), 256, 0, stream>>>(
            hidden, kDModel, w_in, kDModel, proj, kProjW, kRows, kProjW, kDModel, nullptr);
    }

    // 2. depthwise causal conv + SiLU -> u
    {
        int total = kRows * (kDInner / 4);
        conv_silu_kernel<<<(total + 255) / 256, 256, 0, stream>>>(proj, conv_w, conv_b, u);
    }

    // 3. x_proj: xdbl[4096,96] = u @ w_x^T  (fp32)
    gemm_nt_f32<64,64,32,4,4,0><<<dim3((kXdblW + 63)/64, kRows/64), 256, 0, stream>>>(
        u, kDInner, w_x, kDInner, xdbl, kXdblW, kRows, kXdblW, kDInner, nullptr);

    // 4. dt_proj + bias + softplus -> proj[:, 0:2048]  (fp32)
    gemm_nt_f32<128,128,16,8,8,1><<<dim3(kDInner/128, kRows/128), 256, 0, stream>>>(
        xdbl, kXdblW, w_dt, kDtRank, proj, kProjW, kRows, kDInner, kDtRank, b_dt);

    // 5. chunked selective scan (+ skip + gate)
    {
        int n1 = kBatch * kDInner * kDState * kChunks;
        scan_pass1<<<n1 / 256, 256, 0, stream>>>(proj, u, xdbl, A_log, htail, Pprod);
        int n2 = kBatch * kDInner * kDState;
        scan_pass2<<<n2 / 256, 256, 0, stream>>>(htail, Pprod);
        scan_pass3<<<n1 / 256, 256, 0, stream>>>(u, xdbl, A_log, Dskip, htail, proj,
                                                 yh, yl, use_bf16 ? 1 : 0);
    }

    // 6. out_proj
    if (use_bf16) {
        gemm_bf16x3<<<dim3(kDModel/128, kRows/128), 256, 0, stream>>>(
            yh, yl, Woh, Wol, out, kDModel, kDInner);
    } else {
        gemm_nt_f32<128,128,16,8,8,0><<<dim3(kDModel/128, kRows/128), 256, 0, stream>>>(
            proj, kProjW, w_out, kDInner, out, kDModel, kRows, kDModel, kDInner, nullptr);
    }
}

// Round 10
// 658.553 us; speedup vs baseline: 3.8965x; 1.2545x over previous
//
#include <hip/hip_runtime.h>
#include <math.h>

// Problem constants (match reference)
constexpr int kDModel = 1024;
constexpr int kDState = 16;
constexpr int kDConv  = 4;
constexpr int kDInner = 2048;
constexpr int kDtRank = 64;
constexpr int kBatch  = 2;
constexpr int kSeq    = 2048;
constexpr int kRows   = kBatch * kSeq;   // 4096 (B*L)
constexpr int kProjW  = 2 * kDInner;     // 4096
constexpr int kXdblW  = kDtRank + 2 * kDState;  // 96
// chunked scan: one thread per (b, d, chunk), 16 states in registers
constexpr int kChunks = 32;
constexpr int kLc     = kSeq / kChunks;  // 64

__device__ __forceinline__ float sigmoid_f(float x) {
    return 1.0f / (1.0f + __expf(-x));
}
__device__ __forceinline__ float softplus_f(float x) {
    return fmaxf(x, 0.0f) + log1pf(__expf(-fabsf(x)));
}
// fp32 -> bf16 (RNE) and back, as raw ushort bit patterns
__device__ __forceinline__ unsigned short f2bf(float x) {
    unsigned int u = __float_as_uint(x);
    u += 0x7FFFu + ((u >> 16) & 1u);
    return (unsigned short)(u >> 16);
}
__device__ __forceinline__ float bf2f(unsigned short h) {
    return __uint_as_float(((unsigned int)h) << 16);
}

// ---------------------------------------------------------------------------
// Generic tiled fp32 GEMM, "NT" form (kept for x_proj / dt_proj / fallback)
// EPI: 0 = none, 1 = softplus(v + bias[col])
// ---------------------------------------------------------------------------
template<int BM, int BN, int BK, int TM, int TN, int EPI>
__global__ __launch_bounds__((BM/TM)*(BN/TN))
void gemm_nt_f32(const float* __restrict__ A, int lda,
                 const float* __restrict__ B, int ldb,
                 float* __restrict__ C, int ldc,
                 int M, int N, int K,
                 const float* __restrict__ bias)
{
    constexpr int NTHR = (BM/TM)*(BN/TN);
    constexpr int TX   = BN/TN;
    constexpr int KQ   = BK/4;
    constexpr int A_ITERS = (BM*KQ)/NTHR;
    constexpr int B_ITERS = (BN*KQ)/NTHR;
    static_assert((BM*KQ) % NTHR == 0 && (BN*KQ) % NTHR == 0, "loader");

    __shared__ float As[BK][BM];
    __shared__ float Bs[BK][BN];

    const int tid = threadIdx.x;
    const int tx  = tid % TX;
    const int ty  = tid / TX;
    const int bm0 = blockIdx.y * BM;
    const int bn0 = blockIdx.x * BN;

    float acc[TM][TN];
    #pragma unroll
    for (int i = 0; i < TM; ++i)
        #pragma unroll
        for (int j = 0; j < TN; ++j) acc[i][j] = 0.0f;

    for (int kt = 0; kt < K; kt += BK) {
        #pragma unroll
        for (int it = 0; it < A_ITERS; ++it) {
            int c  = tid + it * NTHR;
            int r  = c / KQ;
            int kq = c % KQ;
            float4 v = make_float4(0.f, 0.f, 0.f, 0.f);
            int gm = bm0 + r;
            if (gm < M)
                v = *reinterpret_cast<const float4*>(A + (size_t)gm * lda + kt + kq * 4);
            As[kq*4+0][r] = v.x; As[kq*4+1][r] = v.y;
            As[kq*4+2][r] = v.z; As[kq*4+3][r] = v.w;
        }
        #pragma unroll
        for (int it = 0; it < B_ITERS; ++it) {
            int c  = tid + it * NTHR;
            int r  = c / KQ;
            int kq = c % KQ;
            float4 v = make_float4(0.f, 0.f, 0.f, 0.f);
            int gn = bn0 + r;
            if (gn < N)
                v = *reinterpret_cast<const float4*>(B + (size_t)gn * ldb + kt + kq * 4);
            Bs[kq*4+0][r] = v.x; Bs[kq*4+1][r] = v.y;
            Bs[kq*4+2][r] = v.z; Bs[kq*4+3][r] = v.w;
        }
        __syncthreads();

        #pragma unroll
        for (int k = 0; k < BK; ++k) {
            float a[TM], b[TN];
            #pragma unroll
            for (int i = 0; i < TM/4; ++i) {
                float4 v = *reinterpret_cast<const float4*>(&As[k][ty*TM + i*4]);
                a[i*4+0] = v.x; a[i*4+1] = v.y; a[i*4+2] = v.z; a[i*4+3] = v.w;
            }
            #pragma unroll
            for (int j = 0; j < TN/4; ++j) {
                float4 v = *reinterpret_cast<const float4*>(&Bs[k][tx*TN + j*4]);
                b[j*4+0] = v.x; b[j*4+1] = v.y; b[j*4+2] = v.z; b[j*4+3] = v.w;
            }
            #pragma unroll
            for (int i = 0; i < TM; ++i)
                #pragma unroll
                for (int j = 0; j < TN; ++j)
                    acc[i][j] = fmaf(a[i], b[j], acc[i][j]);
        }
        __syncthreads();
    }

    const bool full = (bm0 + BM <= M) && (bn0 + BN <= N);
    if (full) {
        #pragma unroll
        for (int i = 0; i < TM; ++i) {
            float* cp = C + (size_t)(bm0 + ty*TM + i) * ldc + bn0 + tx*TN;
            #pragma unroll
            for (int j4 = 0; j4 < TN/4; ++j4) {
                int col0 = bn0 + tx*TN + j4*4;
                float e0 = acc[i][j4*4+0], e1 = acc[i][j4*4+1];
                float e2 = acc[i][j4*4+2], e3 = acc[i][j4*4+3];
                if (EPI == 1) {
                    e0 = softplus_f(e0 + bias[col0+0]);
                    e1 = softplus_f(e1 + bias[col0+1]);
                    e2 = softplus_f(e2 + bias[col0+2]);
                    e3 = softplus_f(e3 + bias[col0+3]);
                }
                *reinterpret_cast<float4*>(cp + j4*4) = make_float4(e0, e1, e2, e3);
            }
        }
    } else {
        #pragma unroll
        for (int i = 0; i < TM; ++i) {
            int gm = bm0 + ty*TM + i;
            if (gm >= M) continue;
            #pragma unroll
            for (int j = 0; j < TN; ++j) {
                int gn = bn0 + tx*TN + j;
                if (gn >= N) continue;
                float e = acc[i][j];
                if (EPI == 1) e = softplus_f(e + bias[gn]);
                C[(size_t)gm * ldc + gn] = e;
            }
        }
    }
}

// ---------------------------------------------------------------------------
// bf16x3 split: x -> (hi, lo) bf16 pairs. n must be divisible by 4.
// ---------------------------------------------------------------------------
__global__ __launch_bounds__(256)
void split_bf16_kernel(const float* __restrict__ x,
                       unsigned short* __restrict__ h,
                       unsigned short* __restrict__ l, int n)
{
    int i = (blockIdx.x * blockDim.x + threadIdx.x) * 4;
    if (i >= n) return;
    float4 v = *reinterpret_cast<const float4*>(x + i);
    ushort4 hv, lv;
    hv.x = f2bf(v.x); lv.x = f2bf(v.x - bf2f(hv.x));
    hv.y = f2bf(v.y); lv.y = f2bf(v.y - bf2f(hv.y));
    hv.z = f2bf(v.z); lv.z = f2bf(v.z - bf2f(hv.z));
    hv.w = f2bf(v.w); lv.w = f2bf(v.w - bf2f(hv.w));
    *reinterpret_cast<ushort4*>(h + i) = hv;
    *reinterpret_cast<ushort4*>(l + i) = lv;
}

// ---------------------------------------------------------------------------
// bf16x3 MFMA GEMM (validated r6): C fp32 = A @ B^T, A/B as bf16 hi/lo.
// ---------------------------------------------------------------------------
typedef __attribute__((ext_vector_type(8))) short bf16x8;   // 8 bf16 = 4 VGPR
typedef __attribute__((ext_vector_type(4))) float f32x4;    // C/D frag

__device__ __forceinline__ void gl_lds16(const unsigned short* g, unsigned short* l) {
    __builtin_amdgcn_global_load_lds(
        (const __attribute__((address_space(1))) unsigned int*)g,
        (__attribute__((address_space(3))) unsigned int*)l, 16, 0, 0);
}

__global__ __launch_bounds__(256, 2)
void gemm_bf16x3(const unsigned short* __restrict__ Ah,
                 const unsigned short* __restrict__ Al,
                 const unsigned short* __restrict__ Bh,
                 const unsigned short* __restrict__ Bl,
                 float* __restrict__ C, int ldc, int K)
{
    __shared__ __align__(16) unsigned short sA[2][128*32];  // [hi/lo][row][k]
    __shared__ __align__(16) unsigned short sB[2][128*32];

    const int tid  = threadIdx.x;
    const int w    = tid >> 6;          // wave 0..3
    const int lane = tid & 63;
    const int wr   = w >> 1, wc = w & 1;
    const int brow = blockIdx.y * 128;
    const int bcol = blockIdx.x * 128;

    const int srow = w * 32 + (lane >> 2);     // tile row for this lane
    const int kch  = (lane & 3) * 8;           // bf16 offset within 32-wide k
    const unsigned short* gAh = Ah + (size_t)(brow + srow) * K + kch;
    const unsigned short* gAl = Al + (size_t)(brow + srow) * K + kch;
    const unsigned short* gBh = Bh + (size_t)(bcol + srow) * K + kch;
    const unsigned short* gBl = Bl + (size_t)(bcol + srow) * K + kch;
    unsigned short* lAh = &sA[0][(w*32)*32];
    unsigned short* lAl = &sA[1][(w*32)*32];
    unsigned short* lBh = &sB[0][(w*32)*32];
    unsigned short* lBl = &sB[1][(w*32)*32];

    f32x4 acc[4][4];
    #pragma unroll
    for (int i = 0; i < 4; ++i)
        #pragma unroll
        for (int j = 0; j < 4; ++j) acc[i][j] = (f32x4){0.f, 0.f, 0.f, 0.f};

    const int fr = lane & 15;            // fragment row (m or n within 16)
    const int k8 = (lane >> 4) * 8;      // fragment k offset

    for (int kt = 0; kt < K; kt += 32) {
        gl_lds16(gAh,            lAh);
        gl_lds16(gAh + 16 * K,   lAh + 512);
        gl_lds16(gAl,            lAl);
        gl_lds16(gAl + 16 * K,   lAl + 512);
        gl_lds16(gBh,            lBh);
        gl_lds16(gBh + 16 * K,   lBh + 512);
        gl_lds16(gBl,            lBl);
        gl_lds16(gBl + 16 * K,   lBl + 512);
        gAh += 32; gAl += 32; gBh += 32; gBl += 32;
        asm volatile("s_waitcnt vmcnt(0)" ::: "memory");
        __syncthreads();

        bf16x8 ah[4], al[4], bh[4], bl[4];
        #pragma unroll
        for (int i = 0; i < 4; ++i) {
            int ar = (wr*64 + i*16 + fr) * 32 + k8;
            int br = (wc*64 + i*16 + fr) * 32 + k8;
            ah[i] = *reinterpret_cast<const bf16x8*>(&sA[0][ar]);
            al[i] = *reinterpret_cast<const bf16x8*>(&sA[1][ar]);
            bh[i] = *reinterpret_cast<const bf16x8*>(&sB[0][br]);
            bl[i] = *reinterpret_cast<const bf16x8*>(&sB[1][br]);
        }
        #pragma unroll
        for (int i = 0; i < 4; ++i)
            #pragma unroll
            for (int j = 0; j < 4; ++j) {
                acc[i][j] = __builtin_amdgcn_mfma_f32_16x16x32_bf16(ah[i], bh[j], acc[i][j], 0, 0, 0);
                acc[i][j] = __builtin_amdgcn_mfma_f32_16x16x32_bf16(ah[i], bl[j], acc[i][j], 0, 0, 0);
                acc[i][j] = __builtin_amdgcn_mfma_f32_16x16x32_bf16(al[i], bh[j], acc[i][j], 0, 0, 0);
            }
        __syncthreads();
    }

    // epilogue: C/D layout col = lane&15, row = (lane>>4)*4 + reg  [m89/m91]
    const int crow0 = brow + wr*64 + (lane >> 4) * 4;
    const int ccol0 = bcol + wc*64 + (lane & 15);
    #pragma unroll
    for (int i = 0; i < 4; ++i)
        #pragma unroll
        for (int j = 0; j < 4; ++j) {
            float* cp = C + (size_t)(crow0 + i*16) * ldc + ccol0 + j*16;
            #pragma unroll
            for (int r = 0; r < 4; ++r)
                cp[(size_t)r * ldc] = acc[i][j][r];
        }
}

// ---------------------------------------------------------------------------
// Fused depthwise causal conv1d (k=4) + bias + SiLU (unchanged)
// ---------------------------------------------------------------------------
__global__ __launch_bounds__(256)
void conv_silu_kernel(const float* __restrict__ proj,
                      const float* __restrict__ conv_w,
                      const float* __restrict__ conv_b,
                      float* __restrict__ u)
{
    int idx = blockIdx.x * blockDim.x + threadIdx.x;
    constexpr int D4 = kDInner / 4;
    if (idx >= kRows * D4) return;
    int d4  = idx % D4;
    int row = idx / D4;
    int t   = row % kSeq;
    int d   = d4 * 4;

    float4 w0 = *reinterpret_cast<const float4*>(conv_w + (size_t)(d+0)*4);
    float4 w1 = *reinterpret_cast<const float4*>(conv_w + (size_t)(d+1)*4);
    float4 w2 = *reinterpret_cast<const float4*>(conv_w + (size_t)(d+2)*4);
    float4 w3 = *reinterpret_cast<const float4*>(conv_w + (size_t)(d+3)*4);
    float4 bv = *reinterpret_cast<const float4*>(conv_b + d);
    float a0 = bv.x, a1 = bv.y, a2 = bv.z, a3 = bv.w;

    #pragma unroll
    for (int k = 0; k < kDConv; ++k) {
        int tt = t - (kDConv - 1) + k;
        if (tt < 0) continue;
        const float4 xv = *reinterpret_cast<const float4*>(
            proj + (size_t)(row - (kDConv - 1) + k) * kProjW + d);
        const float wk0 = (&w0.x)[k], wk1 = (&w1.x)[k];
        const float wk2 = (&w2.x)[k], wk3 = (&w3.x)[k];
        a0 = fmaf(xv.x, wk0, a0);
        a1 = fmaf(xv.y, wk1, a1);
        a2 = fmaf(xv.z, wk2, a2);
        a3 = fmaf(xv.w, wk3, a3);
    }
    a0 *= sigmoid_f(a0); a1 *= sigmoid_f(a1);
    a2 *= sigmoid_f(a2); a3 *= sigmoid_f(a3);
    *reinterpret_cast<float4*>(u + (size_t)row * kDInner + d) = make_float4(a0, a1, a2, a3);
}

// ---------------------------------------------------------------------------
// Chunked scan, transposed mapping: one thread per (b, d, chunk), 16 states
// in registers. Per t: dt/u coalesced loads, B/C wave-uniform loads, 16-deep
// unrolled exp/fma chain, no shuffles, no divergence.
// Summary layout: [B, C, S, D] (coalesced in d for pass1/pass3 stores+loads).
// ---------------------------------------------------------------------------
__global__ __launch_bounds__(256)
void scan_pass1(const float* __restrict__ proj,   // dt @ [row*kProjW + d]
                const float* __restrict__ u,      // [kRows, kDInner]
                const float* __restrict__ xdbl,   // [kRows, 96]
                const float* __restrict__ A_log,  // [kDInner, 16]
                float* __restrict__ htail,        // [B, C, S, D]
                float* __restrict__ Pprod)        // [B, C, S, D]
{
    int g = blockIdx.x * blockDim.x + threadIdx.x;   // B*D*C = 131072
    int d = g & (kDInner - 1);
    int c = (g >> 11) & (kChunks - 1);
    int b = g >> 16;

    float Av[kDState];
    {
        const float4* a4 = reinterpret_cast<const float4*>(A_log + (size_t)d * kDState);
        #pragma unroll
        for (int q = 0; q < 4; ++q) {
            float4 v = a4[q];
            Av[q*4+0] = -__expf(v.x); Av[q*4+1] = -__expf(v.y);
            Av[q*4+2] = -__expf(v.z); Av[q*4+3] = -__expf(v.w);
        }
    }

    const int row0 = b * kSeq + c * kLc;
    const float* dt_p = proj + (size_t)row0 * kProjW + d;
    const float* u_p  = u    + (size_t)row0 * kDInner + d;
    const float* bc_p = xdbl + (size_t)row0 * kXdblW + kDtRank;

    float h[kDState], P[kDState];
    #pragma unroll
    for (int s = 0; s < kDState; ++s) { h[s] = 0.0f; P[s] = 1.0f; }

    for (int t = 0; t < kLc; ++t) {
        const float dt_v = *dt_p;
        const float u_v  = *u_p;
        float Bf[kDState];
        {
            const float4* b4 = reinterpret_cast<const float4*>(bc_p);
            #pragma unroll
            for (int q = 0; q < 4; ++q) {
                float4 v = b4[q];
                Bf[q*4+0]=v.x; Bf[q*4+1]=v.y; Bf[q*4+2]=v.z; Bf[q*4+3]=v.w;
            }
        }
        const float dtu = dt_v * u_v;
        #pragma unroll
        for (int s = 0; s < kDState; ++s) {
            const float dA = __expf(dt_v * Av[s]);
            h[s] = fmaf(dA, h[s], dtu * Bf[s]);
            P[s] *= dA;
        }
        dt_p += kProjW; u_p += kDInner; bc_p += kXdblW;
    }

    size_t obase = (((size_t)b * kChunks + c) * kDState) * kDInner + d;
    #pragma unroll
    for (int s = 0; s < kDState; ++s) {
        htail[obase + (size_t)s * kDInner] = h[s];
        Pprod[obase + (size_t)s * kDInner] = P[s];
    }
}

// Pass 2: combine chunk summaries. In: h_local; out: h_init per chunk.
__global__ __launch_bounds__(256)
void scan_pass2(float* hbuf, const float* __restrict__ Pprod)
{
    int tid = blockIdx.x * blockDim.x + threadIdx.x;  // B*S*D = 65536
    int d = tid & (kDInner - 1);
    int s = (tid >> 11) & (kDState - 1);
    int b = tid >> 15;

    float hs = 0.0f;
    for (int c = 0; c < kChunks; ++c) {
        size_t ix = (((size_t)b * kChunks + c) * kDState + s) * kDInner + d;
        const float ht = hbuf[ix];
        const float P  = Pprod[ix];
        hbuf[ix] = hs;               // h_init for chunk c
        hs = fmaf(P, hs, ht);
    }
}

// Pass 3: re-run scan from h_init, fused y-dot + skip + gate.
// bf16_mode: write y as bf16 hi/lo (feeds MFMA out_proj); else fp32 into proj.
__global__ __launch_bounds__(256)
void scan_pass3(const float* __restrict__ u,      // [kRows, kDInner]
                const float* __restrict__ xdbl,   // [kRows, 96]
                const float* __restrict__ A_log,  // [kDInner, 16]
                const float* __restrict__ D_skip, // [kDInner]
                const float* __restrict__ hinit,  // [B, C, S, D]
                float* proj,                      // dt read @ col d; gate @ 2048+d
                unsigned short* __restrict__ yh,
                unsigned short* __restrict__ yl,
                int bf16_mode)
{
    int g = blockIdx.x * blockDim.x + threadIdx.x;   // B*D*C = 131072
    int d = g & (kDInner - 1);
    int c = (g >> 11) & (kChunks - 1);
    int b = g >> 16;

    float Av[kDState];
    {
        const float4* a4 = reinterpret_cast<const float4*>(A_log + (size_t)d * kDState);
        #pragma unroll
        for (int q = 0; q < 4; ++q) {
            float4 v = a4[q];
            Av[q*4+0] = -__expf(v.x); Av[q*4+1] = -__expf(v.y);
            Av[q*4+2] = -__expf(v.z); Av[q*4+3] = -__expf(v.w);
        }
    }
    const float Dv = D_skip[d];

    float h[kDState];
    {
        size_t ibase = (((size_t)b * kChunks + c) * kDState) * kDInner + d;
        #pragma unroll
        for (int s = 0; s < kDState; ++s)
            h[s] = hinit[ibase + (size_t)s * kDInner];
    }

    const int row0 = b * kSeq + c * kLc;
    float*       dt_p = proj + (size_t)row0 * kProjW + d;   // also y dest (fallback)
    const float* u_p  = u    + (size_t)row0 * kDInner + d;
    const float* bc_p = xdbl + (size_t)row0 * kXdblW + kDtRank;
    size_t       yoff = (size_t)row0 * kDInner + d;

    for (int t = 0; t < kLc; ++t) {
        const float dt_v = *dt_p;
        const float u_v  = *u_p;
        float Bf[kDState], Cf[kDState];
        {
            const float4* b4 = reinterpret_cast<const float4*>(bc_p);
            #pragma unroll
            for (int q = 0; q < 4; ++q) {
                float4 v = b4[q];
                Bf[q*4+0]=v.x; Bf[q*4+1]=v.y; Bf[q*4+2]=v.z; Bf[q*4+3]=v.w;
            }
            const float4* c4 = reinterpret_cast<const float4*>(bc_p + kDState);
            #pragma unroll
            for (int q = 0; q < 4; ++q) {
                float4 v = c4[q];
                Cf[q*4+0]=v.x; Cf[q*4+1]=v.y; Cf[q*4+2]=v.z; Cf[q*4+3]=v.w;
            }
        }
        const float dtu = dt_v * u_v;
        float y = 0.0f;
        #pragma unroll
        for (int s = 0; s < kDState; ++s) {
            const float dA = __expf(dt_v * Av[s]);
            h[s] = fmaf(dA, h[s], dtu * Bf[s]);
            y = fmaf(h[s], Cf[s], y);
        }
        const float gt = dt_p[kDInner];   // gate @ col 2048+d
        const float yv = (y + u_v * Dv) * (gt * sigmoid_f(gt));
        if (bf16_mode) {
            unsigned short hv = f2bf(yv);
            yh[yoff] = hv;
            yl[yoff] = f2bf(yv - bf2f(hv));
        } else {
            *dt_p = yv;                   // same thread owns this cell
        }
        dt_p += kProjW; u_p += kDInner; bc_p += kXdblW; yoff += kDInner;
    }
}

// ---------------------------------------------------------------------------
extern "C" void kernel_launch(void* const* d_in, const int* in_sizes, int n_in,
                              void* d_out, int out_size, void* d_ws, size_t ws_size,
                              hipStream_t stream)
{
    const float* hidden  = (const float*)d_in[0];
    const float* w_in    = (const float*)d_in[2];
    const float* conv_w  = (const float*)d_in[3];
    const float* conv_b  = (const float*)d_in[4];
    const float* w_x     = (const float*)d_in[5];
    const float* w_dt    = (const float*)d_in[6];
    const float* b_dt    = (const float*)d_in[7];
    const float* A_log   = (const float*)d_in[8];
    const float* Dskip   = (const float*)d_in[9];
    const float* w_out   = (const float*)d_in[10];
    float* out = (float*)d_out;

    // base ws (floats): proj | u | xdbl | htail          (105.5 MB)
    // Pprod aliases the Ah/Al split region (dead after in_proj, before pass1).
    float* proj  = (float*)d_ws;
    float* u     = proj  + (size_t)kRows * kProjW;
    float* xdbl  = u     + (size_t)kRows * kDInner;
    float* htail = xdbl  + (size_t)kRows * kXdblW;
    float* base_end = htail + (size_t)kBatch * kChunks * kDState * kDInner;

    unsigned short* sp = (unsigned short*)base_end;
    const size_t nHid  = (size_t)kRows * kDModel;      // 4,194,304
    const size_t nWin  = (size_t)kProjW * kDModel;     // 4,194,304
    const size_t nWout = (size_t)kDModel * kDInner;    // 2,097,152
    const size_t nY    = (size_t)kRows * kDInner;      // 8,388,608
    unsigned short* Ah  = sp;
    unsigned short* Al  = Ah + nHid;
    unsigned short* Wh  = Al + nHid;
    unsigned short* Wl  = Wh + nWin;
    float*          Pprod = (float*)sp;      // 2,097,152 floats over Ah/Al (dead)
    unsigned short* yh  = sp;                // pass3 output, over Pprod (dead)
    unsigned short* yl  = sp + nY;           // over Wh/Wl (dead)
    unsigned short* Woh = sp + 2 * nY;
    unsigned short* Wol = Woh + nWout;
    const size_t need_bf16 = (size_t)((char*)(Wol + nWout) - (char*)d_ws);
    const bool use_bf16 = ws_size >= need_bf16;

    if (use_bf16) {
        split_bf16_kernel<<<(int)(nHid / 4 / 256), 256, 0, stream>>>(hidden, Ah, Al, (int)nHid);
        split_bf16_kernel<<<(int)(nWin / 4 / 256), 256, 0, stream>>>(w_in, Wh, Wl, (int)nWin);
        split_bf16_kernel<<<(int)(nWout / 4 / 256), 256, 0, stream>>>(w_out, Woh, Wol, (int)nWout);
        gemm_bf16x3<<<dim3(kProjW/128, kRows/128), 256, 0, stream>>>(
            Ah, Al, Wh, Wl, proj, kProjW, kDModel);
    } else {
        gemm_nt_f32<128,128,16,8,8,0><<<dim3(kProjW/128, kRows/128), 256, 0, stream>>>(
            hidden, kDModel, w_in, kDModel, proj, kProjW, kRows, kProjW, kDModel, nullptr);
    }

    // 2. depthwise causal conv + SiLU -> u
    {
        int total = kRows * (kDInner / 4);
        conv_silu_kernel<<<(total + 255) / 256, 256, 0, stream>>>(proj, conv_w, conv_b, u);
    }

    // 3. x_proj: xdbl[4096,96] = u @ w_x^T  (fp32)
    gemm_nt_f32<64,64,32,4,4,0><<<dim3((kXdblW + 63)/64, kRows/64), 256, 0, stream>>>(
        u, kDInner, w_x, kDInner, xdbl, kXdblW, kRows, kXdblW, kDInner, nullptr);

    // 4. dt_proj + bias + softplus -> proj[:, 0:2048]  (fp32)
    gemm_nt_f32<128,128,16,8,8,1><<<dim3(kDInner/128, kRows/128), 256, 0, stream>>>(
        xdbl, kXdblW, w_dt, kDtRank, proj, kProjW, kRows, kDInner, kDtRank, b_dt);

    // 5. chunked selective scan (+ skip + gate)
    {
        int n1 = kBatch * kDInner * kChunks;             // 131,072 threads
        scan_pass1<<<n1 / 256, 256, 0, stream>>>(proj, u, xdbl, A_log, htail, Pprod);
        int n2 = kBatch * kDInner * kDState;             // 65,536 threads
        scan_pass2<<<n2 / 256, 256, 0, stream>>>(htail, Pprod);
        scan_pass3<<<n1 / 256, 256, 0, stream>>>(u, xdbl, A_log, Dskip, htail, proj,
                                                 yh, yl, use_bf16 ? 1 : 0);
    }

    // 6. out_proj
    if (use_bf16) {
        gemm_bf16x3<<<dim3(kDModel/128, kRows/128), 256, 0, stream>>>(
            yh, yl, Woh, Wol, out, kDModel, kDInner);
    } else {
        gemm_nt_f32<128,128,16,8,8,0><<<dim3(kDModel/128, kRows/128), 256, 0, stream>>>(
            proj, kProjW, w_out, kDInner, out, kDModel, kRows, kDModel, kDInner, nullptr);
    }
}

// Round 12
// 514.412 us; speedup vs baseline: 4.9884x; 1.2802x over previous
//
#include <hip/hip_runtime.h>
#include <math.h>

// Problem constants (match reference)
constexpr int kDModel = 1024;
constexpr int kDState = 16;
constexpr int kDConv  = 4;
constexpr int kDInner = 2048;
constexpr int kDtRank = 64;
constexpr int kBatch  = 2;
constexpr int kSeq    = 2048;
constexpr int kRows   = kBatch * kSeq;   // 4096 (B*L)
constexpr int kProjW  = 2 * kDInner;     // 4096
constexpr int kXdblW  = kDtRank + 2 * kDState;  // 96
// chunked scan: one thread per (b, d, chunk), 16 states in registers
constexpr int kChunks = 32;
constexpr int kLc     = kSeq / kChunks;  // 64
// x_proj split-K
constexpr int XP_ROWS = 64;   // rows per tile
constexpr int XP_KS   = 16;   // k slices
constexpr int XP_KC   = 128;  // k per slice
constexpr int XP_KH   = 64;   // k per staged half

__device__ __forceinline__ float sigmoid_f(float x) {
    return 1.0f / (1.0f + __expf(-x));
}
__device__ __forceinline__ float softplus_f(float x) {
    return fmaxf(x, 0.0f) + log1pf(__expf(-fabsf(x)));
}
// fp32 -> bf16 (RNE) and back, as raw ushort bit patterns
__device__ __forceinline__ unsigned short f2bf(float x) {
    unsigned int u = __float_as_uint(x);
    u += 0x7FFFu + ((u >> 16) & 1u);
    return (unsigned short)(u >> 16);
}
__device__ __forceinline__ float bf2f(unsigned short h) {
    return __uint_as_float(((unsigned int)h) << 16);
}

// ---------------------------------------------------------------------------
// Generic tiled fp32 GEMM, "NT" form (kept for dt_proj / fallback)
// EPI: 0 = none, 1 = softplus(v + bias[col])
// ---------------------------------------------------------------------------
template<int BM, int BN, int BK, int TM, int TN, int EPI>
__global__ __launch_bounds__((BM/TM)*(BN/TN))
void gemm_nt_f32(const float* __restrict__ A, int lda,
                 const float* __restrict__ B, int ldb,
                 float* __restrict__ C, int ldc,
                 int M, int N, int K,
                 const float* __restrict__ bias)
{
    constexpr int NTHR = (BM/TM)*(BN/TN);
    constexpr int TX   = BN/TN;
    constexpr int KQ   = BK/4;
    constexpr int A_ITERS = (BM*KQ)/NTHR;
    constexpr int B_ITERS = (BN*KQ)/NTHR;
    static_assert((BM*KQ) % NTHR == 0 && (BN*KQ) % NTHR == 0, "loader");

    __shared__ float As[BK][BM];
    __shared__ float Bs[BK][BN];

    const int tid = threadIdx.x;
    const int tx  = tid % TX;
    const int ty  = tid / TX;
    const int bm0 = blockIdx.y * BM;
    const int bn0 = blockIdx.x * BN;

    float acc[TM][TN];
    #pragma unroll
    for (int i = 0; i < TM; ++i)
        #pragma unroll
        for (int j = 0; j < TN; ++j) acc[i][j] = 0.0f;

    for (int kt = 0; kt < K; kt += BK) {
        #pragma unroll
        for (int it = 0; it < A_ITERS; ++it) {
            int c  = tid + it * NTHR;
            int r  = c / KQ;
            int kq = c % KQ;
            float4 v = make_float4(0.f, 0.f, 0.f, 0.f);
            int gm = bm0 + r;
            if (gm < M)
                v = *reinterpret_cast<const float4*>(A + (size_t)gm * lda + kt + kq * 4);
            As[kq*4+0][r] = v.x; As[kq*4+1][r] = v.y;
            As[kq*4+2][r] = v.z; As[kq*4+3][r] = v.w;
        }
        #pragma unroll
        for (int it = 0; it < B_ITERS; ++it) {
            int c  = tid + it * NTHR;
            int r  = c / KQ;
            int kq = c % KQ;
            float4 v = make_float4(0.f, 0.f, 0.f, 0.f);
            int gn = bn0 + r;
            if (gn < N)
                v = *reinterpret_cast<const float4*>(B + (size_t)gn * ldb + kt + kq * 4);
            Bs[kq*4+0][r] = v.x; Bs[kq*4+1][r] = v.y;
            Bs[kq*4+2][r] = v.z; Bs[kq*4+3][r] = v.w;
        }
        __syncthreads();

        #pragma unroll
        for (int k = 0; k < BK; ++k) {
            float a[TM], b[TN];
            #pragma unroll
            for (int i = 0; i < TM/4; ++i) {
                float4 v = *reinterpret_cast<const float4*>(&As[k][ty*TM + i*4]);
                a[i*4+0] = v.x; a[i*4+1] = v.y; a[i*4+2] = v.z; a[i*4+3] = v.w;
            }
            #pragma unroll
            for (int j = 0; j < TN/4; ++j) {
                float4 v = *reinterpret_cast<const float4*>(&Bs[k][tx*TN + j*4]);
                b[j*4+0] = v.x; b[j*4+1] = v.y; b[j*4+2] = v.z; b[j*4+3] = v.w;
            }
            #pragma unroll
            for (int i = 0; i < TM; ++i)
                #pragma unroll
                for (int j = 0; j < TN; ++j)
                    acc[i][j] = fmaf(a[i], b[j], acc[i][j]);
        }
        __syncthreads();
    }

    const bool full = (bm0 + BM <= M) && (bn0 + BN <= N);
    if (full) {
        #pragma unroll
        for (int i = 0; i < TM; ++i) {
            float* cp = C + (size_t)(bm0 + ty*TM + i) * ldc + bn0 + tx*TN;
            #pragma unroll
            for (int j4 = 0; j4 < TN/4; ++j4) {
                int col0 = bn0 + tx*TN + j4*4;
                float e0 = acc[i][j4*4+0], e1 = acc[i][j4*4+1];
                float e2 = acc[i][j4*4+2], e3 = acc[i][j4*4+3];
                if (EPI == 1) {
                    e0 = softplus_f(e0 + bias[col0+0]);
                    e1 = softplus_f(e1 + bias[col0+1]);
                    e2 = softplus_f(e2 + bias[col0+2]);
                    e3 = softplus_f(e3 + bias[col0+3]);
                }
                *reinterpret_cast<float4*>(cp + j4*4) = make_float4(e0, e1, e2, e3);
            }
        }
    } else {
        #pragma unroll
        for (int i = 0; i < TM; ++i) {
            int gm = bm0 + ty*TM + i;
            if (gm >= M) continue;
            #pragma unroll
            for (int j = 0; j < TN; ++j) {
                int gn = bn0 + tx*TN + j;
                if (gn >= N) continue;
                float e = acc[i][j];
                if (EPI == 1) e = softplus_f(e + bias[gn]);
                C[(size_t)gm * ldc + gn] = e;
            }
        }
    }
}

// ---------------------------------------------------------------------------
// x_proj split-K: part[ks][4096][96] = u[:, ks*128:(ks+1)*128] @ w_x^T slice.
// Grid (64 row-tiles, 16 k-slices) = 1024 blocks. Thread (tx=tid&15, ty=tid>>4)
// owns rows {ty+16i} x cols {tx+16j}: a-reads broadcast (conflict-free banks
// 4ty+k), b-reads stride-68 -> banks (17*tx)%32 all distinct. 24 acc.
// ---------------------------------------------------------------------------
__global__ __launch_bounds__(256)
void xproj_splitk(const float* __restrict__ u,    // [4096][2048]
                  const float* __restrict__ w_x,  // [96][2048]
                  float* __restrict__ part)       // [16][4096][96]
{
    __shared__ float Us[XP_ROWS][XP_KH + 4];   // 64 x 68  (17.4 KB)
    __shared__ float Ws[kXdblW][XP_KH + 4];    // 96 x 68  (26.1 KB)

    const int rt  = blockIdx.x;
    const int ks  = blockIdx.y;
    const int tid = threadIdx.x;
    const int tx  = tid & 15;
    const int ty  = tid >> 4;
    const int row0 = rt * XP_ROWS;
    const int k0   = ks * XP_KC;

    float acc[4][6];
    #pragma unroll
    for (int i = 0; i < 4; ++i)
        #pragma unroll
        for (int j = 0; j < 6; ++j) acc[i][j] = 0.0f;

    for (int half = 0; half < 2; ++half) {
        const int kh = k0 + half * XP_KH;
        // stage u tile: 64 rows x 64 k = 1024 float4, 4/thread, coalesced
        #pragma unroll
        for (int it = 0; it < 4; ++it) {
            int c = tid + it * 256;
            int r = c >> 4;
            int q = c & 15;
            float4 v = *reinterpret_cast<const float4*>(
                u + (size_t)(row0 + r) * kDInner + kh + q * 4);
            *reinterpret_cast<float4*>(&Us[r][q * 4]) = v;
        }
        // stage w tile: 96 rows x 64 k = 1536 float4, 6/thread
        #pragma unroll
        for (int it = 0; it < 6; ++it) {
            int c = tid + it * 256;
            int r = c >> 4;
            int q = c & 15;
            float4 v = *reinterpret_cast<const float4*>(
                w_x + (size_t)r * kDInner + kh + q * 4);
            *reinterpret_cast<float4*>(&Ws[r][q * 4]) = v;
        }
        __syncthreads();

        for (int k = 0; k < XP_KH; k += 4) {
            float4 a4[4], b4[6];
            #pragma unroll
            for (int i = 0; i < 4; ++i)
                a4[i] = *reinterpret_cast<const float4*>(&Us[ty + 16*i][k]);
            #pragma unroll
            for (int j = 0; j < 6; ++j)
                b4[j] = *reinterpret_cast<const float4*>(&Ws[tx + 16*j][k]);
            #pragma unroll
            for (int i = 0; i < 4; ++i)
                #pragma unroll
                for (int j = 0; j < 6; ++j) {
                    acc[i][j] = fmaf(a4[i].x, b4[j].x, acc[i][j]);
                    acc[i][j] = fmaf(a4[i].y, b4[j].y, acc[i][j]);
                    acc[i][j] = fmaf(a4[i].z, b4[j].z, acc[i][j]);
                    acc[i][j] = fmaf(a4[i].w, b4[j].w, acc[i][j]);
                }
        }
        __syncthreads();
    }

    float* pp = part + ((size_t)ks * kRows + row0) * kXdblW;
    #pragma unroll
    for (int i = 0; i < 4; ++i)
        #pragma unroll
        for (int j = 0; j < 6; ++j)
            pp[(size_t)(ty + 16*i) * kXdblW + tx + 16*j] = acc[i][j];
}

// Reduce the 16 k-slice partials into xdbl. Coalesced.
__global__ __launch_bounds__(256)
void xproj_reduce(const float* __restrict__ part, float* __restrict__ xdbl)
{
    int i = blockIdx.x * blockDim.x + threadIdx.x;   // kRows*kXdblW = 393216
    float s = 0.0f;
    #pragma unroll
    for (int ks = 0; ks < XP_KS; ++ks)
        s += part[(size_t)ks * kRows * kXdblW + i];
    xdbl[i] = s;
}

// ---------------------------------------------------------------------------
// bf16x3 split: x -> (hi, lo) bf16 pairs. n must be divisible by 4.
// ---------------------------------------------------------------------------
__global__ __launch_bounds__(256)
void split_bf16_kernel(const float* __restrict__ x,
                       unsigned short* __restrict__ h,
                       unsigned short* __restrict__ l, int n)
{
    int i = (blockIdx.x * blockDim.x + threadIdx.x) * 4;
    if (i >= n) return;
    float4 v = *reinterpret_cast<const float4*>(x + i);
    ushort4 hv, lv;
    hv.x = f2bf(v.x); lv.x = f2bf(v.x - bf2f(hv.x));
    hv.y = f2bf(v.y); lv.y = f2bf(v.y - bf2f(hv.y));
    hv.z = f2bf(v.z); lv.z = f2bf(v.z - bf2f(hv.z));
    hv.w = f2bf(v.w); lv.w = f2bf(v.w - bf2f(hv.w));
    *reinterpret_cast<ushort4*>(h + i) = hv;
    *reinterpret_cast<ushort4*>(l + i) = lv;
}

// ---------------------------------------------------------------------------
// bf16x3 MFMA GEMM (validated r6): C fp32 = A @ B^T, A/B as bf16 hi/lo.
// ---------------------------------------------------------------------------
typedef __attribute__((ext_vector_type(8))) short bf16x8;   // 8 bf16 = 4 VGPR
typedef __attribute__((ext_vector_type(4))) float f32x4;    // C/D frag

__device__ __forceinline__ void gl_lds16(const unsigned short* g, unsigned short* l) {
    __builtin_amdgcn_global_load_lds(
        (const __attribute__((address_space(1))) unsigned int*)g,
        (__attribute__((address_space(3))) unsigned int*)l, 16, 0, 0);
}

__global__ __launch_bounds__(256, 2)
void gemm_bf16x3(const unsigned short* __restrict__ Ah,
                 const unsigned short* __restrict__ Al,
                 const unsigned short* __restrict__ Bh,
                 const unsigned short* __restrict__ Bl,
                 float* __restrict__ C, int ldc, int K)
{
    __shared__ __align__(16) unsigned short sA[2][128*32];  // [hi/lo][row][k]
    __shared__ __align__(16) unsigned short sB[2][128*32];

    const int tid  = threadIdx.x;
    const int w    = tid >> 6;          // wave 0..3
    const int lane = tid & 63;
    const int wr   = w >> 1, wc = w & 1;
    const int brow = blockIdx.y * 128;
    const int bcol = blockIdx.x * 128;

    const int srow = w * 32 + (lane >> 2);     // tile row for this lane
    const int kch  = (lane & 3) * 8;           // bf16 offset within 32-wide k
    const unsigned short* gAh = Ah + (size_t)(brow + srow) * K + kch;
    const unsigned short* gAl = Al + (size_t)(brow + srow) * K + kch;
    const unsigned short* gBh = Bh + (size_t)(bcol + srow) * K + kch;
    const unsigned short* gBl = Bl + (size_t)(bcol + srow) * K + kch;
    unsigned short* lAh = &sA[0][(w*32)*32];
    unsigned short* lAl = &sA[1][(w*32)*32];
    unsigned short* lBh = &sB[0][(w*32)*32];
    unsigned short* lBl = &sB[1][(w*32)*32];

    f32x4 acc[4][4];
    #pragma unroll
    for (int i = 0; i < 4; ++i)
        #pragma unroll
        for (int j = 0; j < 4; ++j) acc[i][j] = (f32x4){0.f, 0.f, 0.f, 0.f};

    const int fr = lane & 15;            // fragment row (m or n within 16)
    const int k8 = (lane >> 4) * 8;      // fragment k offset

    for (int kt = 0; kt < K; kt += 32) {
        gl_lds16(gAh,            lAh);
        gl_lds16(gAh + 16 * K,   lAh + 512);
        gl_lds16(gAl,            lAl);
        gl_lds16(gAl + 16 * K,   lAl + 512);
        gl_lds16(gBh,            lBh);
        gl_lds16(gBh + 16 * K,   lBh + 512);
        gl_lds16(gBl,            lBl);
        gl_lds16(gBl + 16 * K,   lBl + 512);
        gAh += 32; gAl += 32; gBh += 32; gBl += 32;
        asm volatile("s_waitcnt vmcnt(0)" ::: "memory");
        __syncthreads();

        bf16x8 ah[4], al[4], bh[4], bl[4];
        #pragma unroll
        for (int i = 0; i < 4; ++i) {
            int ar = (wr*64 + i*16 + fr) * 32 + k8;
            int br = (wc*64 + i*16 + fr) * 32 + k8;
            ah[i] = *reinterpret_cast<const bf16x8*>(&sA[0][ar]);
            al[i] = *reinterpret_cast<const bf16x8*>(&sA[1][ar]);
            bh[i] = *reinterpret_cast<const bf16x8*>(&sB[0][br]);
            bl[i] = *reinterpret_cast<const bf16x8*>(&sB[1][br]);
        }
        #pragma unroll
        for (int i = 0; i < 4; ++i)
            #pragma unroll
            for (int j = 0; j < 4; ++j) {
                acc[i][j] = __builtin_amdgcn_mfma_f32_16x16x32_bf16(ah[i], bh[j], acc[i][j], 0, 0, 0);
                acc[i][j] = __builtin_amdgcn_mfma_f32_16x16x32_bf16(ah[i], bl[j], acc[i][j], 0, 0, 0);
                acc[i][j] = __builtin_amdgcn_mfma_f32_16x16x32_bf16(al[i], bh[j], acc[i][j], 0, 0, 0);
            }
        __syncthreads();
    }

    // epilogue: C/D layout col = lane&15, row = (lane>>4)*4 + reg  [m89/m91]
    const int crow0 = brow + wr*64 + (lane >> 4) * 4;
    const int ccol0 = bcol + wc*64 + (lane & 15);
    #pragma unroll
    for (int i = 0; i < 4; ++i)
        #pragma unroll
        for (int j = 0; j < 4; ++j) {
            float* cp = C + (size_t)(crow0 + i*16) * ldc + ccol0 + j*16;
            #pragma unroll
            for (int r = 0; r < 4; ++r)
                cp[(size_t)r * ldc] = acc[i][j][r];
        }
}

// ---------------------------------------------------------------------------
// Fused depthwise causal conv1d (k=4) + bias + SiLU (unchanged)
// ---------------------------------------------------------------------------
__global__ __launch_bounds__(256)
void conv_silu_kernel(const float* __restrict__ proj,
                      const float* __restrict__ conv_w,
                      const float* __restrict__ conv_b,
                      float* __restrict__ u)
{
    int idx = blockIdx.x * blockDim.x + threadIdx.x;
    constexpr int D4 = kDInner / 4;
    if (idx >= kRows * D4) return;
    int d4  = idx % D4;
    int row = idx / D4;
    int t   = row % kSeq;
    int d   = d4 * 4;

    float4 w0 = *reinterpret_cast<const float4*>(conv_w + (size_t)(d+0)*4);
    float4 w1 = *reinterpret_cast<const float4*>(conv_w + (size_t)(d+1)*4);
    float4 w2 = *reinterpret_cast<const float4*>(conv_w + (size_t)(d+2)*4);
    float4 w3 = *reinterpret_cast<const float4*>(conv_w + (size_t)(d+3)*4);
    float4 bv = *reinterpret_cast<const float4*>(conv_b + d);
    float a0 = bv.x, a1 = bv.y, a2 = bv.z, a3 = bv.w;

    #pragma unroll
    for (int k = 0; k < kDConv; ++k) {
        int tt = t - (kDConv - 1) + k;
        if (tt < 0) continue;
        const float4 xv = *reinterpret_cast<const float4*>(
            proj + (size_t)(row - (kDConv - 1) + k) * kProjW + d);
        const float wk0 = (&w0.x)[k], wk1 = (&w1.x)[k];
        const float wk2 = (&w2.x)[k], wk3 = (&w3.x)[k];
        a0 = fmaf(xv.x, wk0, a0);
        a1 = fmaf(xv.y, wk1, a1);
        a2 = fmaf(xv.z, wk2, a2);
        a3 = fmaf(xv.w, wk3, a3);
    }
    a0 *= sigmoid_f(a0); a1 *= sigmoid_f(a1);
    a2 *= sigmoid_f(a2); a3 *= sigmoid_f(a3);
    *reinterpret_cast<float4*>(u + (size_t)row * kDInner + d) = make_float4(a0, a1, a2, a3);
}

// ---------------------------------------------------------------------------
// Chunked scan, transposed mapping (validated r10): one thread per (b,d,chunk),
// 16 states in registers. Summary layout [B, C, S, D].
// ---------------------------------------------------------------------------
__global__ __launch_bounds__(256)
void scan_pass1(const float* __restrict__ proj,   // dt @ [row*kProjW + d]
                const float* __restrict__ u,      // [kRows, kDInner]
                const float* __restrict__ xdbl,   // [kRows, 96]
                const float* __restrict__ A_log,  // [kDInner, 16]
                float* __restrict__ htail,        // [B, C, S, D]
                float* __restrict__ Pprod)        // [B, C, S, D]
{
    int g = blockIdx.x * blockDim.x + threadIdx.x;   // B*D*C = 131072
    int d = g & (kDInner - 1);
    int c = (g >> 11) & (kChunks - 1);
    int b = g >> 16;

    float Av[kDState];
    {
        const float4* a4 = reinterpret_cast<const float4*>(A_log + (size_t)d * kDState);
        #pragma unroll
        for (int q = 0; q < 4; ++q) {
            float4 v = a4[q];
            Av[q*4+0] = -__expf(v.x); Av[q*4+1] = -__expf(v.y);
            Av[q*4+2] = -__expf(v.z); Av[q*4+3] = -__expf(v.w);
        }
    }

    const int row0 = b * kSeq + c * kLc;
    const float* dt_p = proj + (size_t)row0 * kProjW + d;
    const float* u_p  = u    + (size_t)row0 * kDInner + d;
    const float* bc_p = xdbl + (size_t)row0 * kXdblW + kDtRank;

    float h[kDState], P[kDState];
    #pragma unroll
    for (int s = 0; s < kDState; ++s) { h[s] = 0.0f; P[s] = 1.0f; }

    for (int t = 0; t < kLc; ++t) {
        const float dt_v = *dt_p;
        const float u_v  = *u_p;
        float Bf[kDState];
        {
            const float4* b4 = reinterpret_cast<const float4*>(bc_p);
            #pragma unroll
            for (int q = 0; q < 4; ++q) {
                float4 v = b4[q];
                Bf[q*4+0]=v.x; Bf[q*4+1]=v.y; Bf[q*4+2]=v.z; Bf[q*4+3]=v.w;
            }
        }
        const float dtu = dt_v * u_v;
        #pragma unroll
        for (int s = 0; s < kDState; ++s) {
            const float dA = __expf(dt_v * Av[s]);
            h[s] = fmaf(dA, h[s], dtu * Bf[s]);
            P[s] *= dA;
        }
        dt_p += kProjW; u_p += kDInner; bc_p += kXdblW;
    }

    size_t obase = (((size_t)b * kChunks + c) * kDState) * kDInner + d;
    #pragma unroll
    for (int s = 0; s < kDState; ++s) {
        htail[obase + (size_t)s * kDInner] = h[s];
        Pprod[obase + (size_t)s * kDInner] = P[s];
    }
}

// Pass 2: combine chunk summaries. In: h_local; out: h_init per chunk.
__global__ __launch_bounds__(256)
void scan_pass2(float* hbuf, const float* __restrict__ Pprod)
{
    int tid = blockIdx.x * blockDim.x + threadIdx.x;  // B*S*D = 65536
    int d = tid & (kDInner - 1);
    int s = (tid >> 11) & (kDState - 1);
    int b = tid >> 15;

    float hs = 0.0f;
    for (int c = 0; c < kChunks; ++c) {
        size_t ix = (((size_t)b * kChunks + c) * kDState + s) * kDInner + d;
        const float ht = hbuf[ix];
        const float P  = Pprod[ix];
        hbuf[ix] = hs;               // h_init for chunk c
        hs = fmaf(P, hs, ht);
    }
}

// Pass 3: re-run scan from h_init, fused y-dot + skip + gate.
// bf16_mode: write y as bf16 hi/lo (feeds MFMA out_proj); else fp32 into proj.
__global__ __launch_bounds__(256)
void scan_pass3(const float* __restrict__ u,      // [kRows, kDInner]
                const float* __restrict__ xdbl,   // [kRows, 96]
                const float* __restrict__ A_log,  // [kDInner, 16]
                const float* __restrict__ D_skip, // [kDInner]
                const float* __restrict__ hinit,  // [B, C, S, D]
                float* proj,                      // dt read @ col d; gate @ 2048+d
                unsigned short* __restrict__ yh,
                unsigned short* __restrict__ yl,
                int bf16_mode)
{
    int g = blockIdx.x * blockDim.x + threadIdx.x;   // B*D*C = 131072
    int d = g & (kDInner - 1);
    int c = (g >> 11) & (kChunks - 1);
    int b = g >> 16;

    float Av[kDState];
    {
        const float4* a4 = reinterpret_cast<const float4*>(A_log + (size_t)d * kDState);
        #pragma unroll
        for (int q = 0; q < 4; ++q) {
            float4 v = a4[q];
            Av[q*4+0] = -__expf(v.x); Av[q*4+1] = -__expf(v.y);
            Av[q*4+2] = -__expf(v.z); Av[q*4+3] = -__expf(v.w);
        }
    }
    const float Dv = D_skip[d];

    float h[kDState];
    {
        size_t ibase = (((size_t)b * kChunks + c) * kDState) * kDInner + d;
        #pragma unroll
        for (int s = 0; s < kDState; ++s)
            h[s] = hinit[ibase + (size_t)s * kDInner];
    }

    const int row0 = b * kSeq + c * kLc;
    float*       dt_p = proj + (size_t)row0 * kProjW + d;   // also y dest (fallback)
    const float* u_p  = u    + (size_t)row0 * kDInner + d;
    const float* bc_p = xdbl + (size_t)row0 * kXdblW + kDtRank;
    size_t       yoff = (size_t)row0 * kDInner + d;

    for (int t = 0; t < kLc; ++t) {
        const float dt_v = *dt_p;
        const float u_v  = *u_p;
        float Bf[kDState], Cf[kDState];
        {
            const float4* b4 = reinterpret_cast<const float4*>(bc_p);
            #pragma unroll
            for (int q = 0; q < 4; ++q) {
                float4 v = b4[q];
                Bf[q*4+0]=v.x; Bf[q*4+1]=v.y; Bf[q*4+2]=v.z; Bf[q*4+3]=v.w;
            }
            const float4* c4 = reinterpret_cast<const float4*>(bc_p + kDState);
            #pragma unroll
            for (int q = 0; q < 4; ++q) {
                float4 v = c4[q];
                Cf[q*4+0]=v.x; Cf[q*4+1]=v.y; Cf[q*4+2]=v.z; Cf[q*4+3]=v.w;
            }
        }
        const float dtu = dt_v * u_v;
        float y = 0.0f;
        #pragma unroll
        for (int s = 0; s < kDState; ++s) {
            const float dA = __expf(dt_v * Av[s]);
            h[s] = fmaf(dA, h[s], dtu * Bf[s]);
            y = fmaf(h[s], Cf[s], y);
        }
        const float gt = dt_p[kDInner];   // gate @ col 2048+d
        const float yv = (y + u_v * Dv) * (gt * sigmoid_f(gt));
        if (bf16_mode) {
            unsigned short hv = f2bf(yv);
            yh[yoff] = hv;
            yl[yoff] = f2bf(yv - bf2f(hv));
        } else {
            *dt_p = yv;                   // same thread owns this cell
        }
        dt_p += kProjW; u_p += kDInner; bc_p += kXdblW; yoff += kDInner;
    }
}

// ---------------------------------------------------------------------------
extern "C" void kernel_launch(void* const* d_in, const int* in_sizes, int n_in,
                              void* d_out, int out_size, void* d_ws, size_t ws_size,
                              hipStream_t stream)
{
    const float* hidden  = (const float*)d_in[0];
    const float* w_in    = (const float*)d_in[2];
    const float* conv_w  = (const float*)d_in[3];
    const float* conv_b  = (const float*)d_in[4];
    const float* w_x     = (const float*)d_in[5];
    const float* w_dt    = (const float*)d_in[6];
    const float* b_dt    = (const float*)d_in[7];
    const float* A_log   = (const float*)d_in[8];
    const float* Dskip   = (const float*)d_in[9];
    const float* w_out   = (const float*)d_in[10];
    float* out = (float*)d_out;

    // base ws (floats): proj | u | xdbl | htail          (105.5 MB)
    // Dead-region reuse ledger (stream-serialized):
    //   sp (40 MB) holds Ah|Al|Wh|Wl during splits+in_proj; then
    //   x_proj partials (25 MB, dead after reduce); then Pprod (8 MB,
    //   dead after pass2); then yh|yl (32 MB, pass3 -> out_proj).
    //   Woh|Wol (8 MB) live at sp+32MB for the whole call.
    float* proj  = (float*)d_ws;
    float* u     = proj  + (size_t)kRows * kProjW;
    float* xdbl  = u     + (size_t)kRows * kDInner;
    float* htail = xdbl  + (size_t)kRows * kXdblW;
    float* base_end = htail + (size_t)kBatch * kChunks * kDState * kDInner;

    unsigned short* sp = (unsigned short*)base_end;
    const size_t nHid  = (size_t)kRows * kDModel;      // 4,194,304
    const size_t nWin  = (size_t)kProjW * kDModel;     // 4,194,304
    const size_t nWout = (size_t)kDModel * kDInner;    // 2,097,152
    const size_t nY    = (size_t)kRows * kDInner;      // 8,388,608
    unsigned short* Ah  = sp;
    unsigned short* Al  = Ah + nHid;
    unsigned short* Wh  = Al + nHid;
    unsigned short* Wl  = Wh + nWin;
    float*          xpart = (float*)sp;      // 6,291,456 floats (25 MB) over Ah..Wh (dead)
    float*          Pprod = (float*)sp;      // 2,097,152 floats over Ah/Al (dead)
    unsigned short* yh  = sp;                // pass3 output, over Pprod (dead)
    unsigned short* yl  = sp + nY;           // over Wh/Wl (dead)
    unsigned short* Woh = sp + 2 * nY;
    unsigned short* Wol = Woh + nWout;
    const size_t need_bf16 = (size_t)((char*)(Wol + nWout) - (char*)d_ws);
    const bool use_bf16 = ws_size >= need_bf16;

    if (use_bf16) {
        split_bf16_kernel<<<(int)(nHid / 4 / 256), 256, 0, stream>>>(hidden, Ah, Al, (int)nHid);
        split_bf16_kernel<<<(int)(nWin / 4 / 256), 256, 0, stream>>>(w_in, Wh, Wl, (int)nWin);
        split_bf16_kernel<<<(int)(nWout / 4 / 256), 256, 0, stream>>>(w_out, Woh, Wol, (int)nWout);
        gemm_bf16x3<<<dim3(kProjW/128, kRows/128), 256, 0, stream>>>(
            Ah, Al, Wh, Wl, proj, kProjW, kDModel);
    } else {
        gemm_nt_f32<128,128,16,8,8,0><<<dim3(kProjW/128, kRows/128), 256, 0, stream>>>(
            hidden, kDModel, w_in, kDModel, proj, kProjW, kRows, kProjW, kDModel, nullptr);
    }

    // 2. depthwise causal conv + SiLU -> u
    {
        int total = kRows * (kDInner / 4);
        conv_silu_kernel<<<(total + 255) / 256, 256, 0, stream>>>(proj, conv_w, conv_b, u);
    }

    // 3. x_proj via split-K (1024 blocks) + reduce -> xdbl
    xproj_splitk<<<dim3(kRows / XP_ROWS, XP_KS), 256, 0, stream>>>(u, w_x, xpart);
    xproj_reduce<<<(kRows * kXdblW) / 256, 256, 0, stream>>>(xpart, xdbl);

    // 4. dt_proj + bias + softplus -> proj[:, 0:2048]  (fp32)
    gemm_nt_f32<128,128,16,8,8,1><<<dim3(kDInner/128, kRows/128), 256, 0, stream>>>(
        xdbl, kXdblW, w_dt, kDtRank, proj, kProjW, kRows, kDInner, kDtRank, b_dt);

    // 5. chunked selective scan (+ skip + gate)
    {
        int n1 = kBatch * kDInner * kChunks;             // 131,072 threads
        scan_pass1<<<n1 / 256, 256, 0, stream>>>(proj, u, xdbl, A_log, htail, Pprod);
        int n2 = kBatch * kDInner * kDState;             // 65,536 threads
        scan_pass2<<<n2 / 256, 256, 0, stream>>>(htail, Pprod);
        scan_pass3<<<n1 / 256, 256, 0, stream>>>(u, xdbl, A_log, Dskip, htail, proj,
                                                 yh, yl, use_bf16 ? 1 : 0);
    }

    // 6. out_proj
    if (use_bf16) {
        gemm_bf16x3<<<dim3(kDModel/128, kRows/128), 256, 0, stream>>>(
            yh, yl, Woh, Wol, out, kDModel, kDInner);
    } else {
        gemm_nt_f32<128,128,16,8,8,0><<<dim3(kDModel/128, kRows/128), 256, 0, stream>>>(
            proj, kProjW, w_out, kDInner, out, kDModel, kRows, kDModel, kDInner, nullptr);
    }
}